// Round 7
// baseline (525.126 us; speedup 1.0000x reference)
//
#include <hip/hip_runtime.h>
#include <math.h>

#define T 1024
#define H 1024
#define NH 8
#define NKV 4
#define HD 128
#define NE 32
#define TOPK 4
#define NG 8
#define MI 512
#define SI 1024
#define RSF 2.5f
#define EPS 1e-6f

// attention split-K params
#define ASPLIT 4
#define SPLITK 256
#define NPSLOT 40  // compact partial slots per head: sum_{qb<16} (qb/4+1)

// padded LDS row stride (shorts) for reg-staged MFMA tiles: 80 B rows, 16 B aligned
#define KP 40

typedef short bf16x8 __attribute__((ext_vector_type(8)));
typedef float f32x4 __attribute__((ext_vector_type(4)));
#define MFMA16(a, b, c) __builtin_amdgcn_mfma_f32_16x16x32_bf16((a), (b), (c), 0, 0, 0)

__device__ inline unsigned short f2bf(float x) {
    unsigned u = __float_as_uint(x);
    u += 0x7fff + ((u >> 16) & 1);  // RNE
    return (unsigned short)(u >> 16);
}
__device__ inline float bf2f(unsigned short h) { return __uint_as_float(((unsigned)h) << 16); }

// compact causal split-slot prefix: C(qb) = sum_{j<qb}(j/4+1)
__device__ __host__ inline int cqb_of(int qb) {
    int a = qb >> 2, r = qb & 3;
    return (a + 1) * (2 * a + r);
}

union U16S {
    unsigned short s[16];
    uint4 q[2];
};

// ---------------- rmsnorm -> bf16 hi/lo split output ----------------
__global__ void rmsnorm_split_kernel(const float* __restrict__ x, const float* __restrict__ w,
                                     unsigned short* __restrict__ oh,
                                     unsigned short* __restrict__ ol) {
    int t = blockIdx.x;
    __shared__ float red[256];
    const float* xr = x + (size_t)t * H;
    float s = 0.f;
    for (int i = threadIdx.x; i < H; i += 256) { float v = xr[i]; s += v * v; }
    red[threadIdx.x] = s;
    __syncthreads();
    for (int st = 128; st > 0; st >>= 1) {
        if (threadIdx.x < st) red[threadIdx.x] += red[threadIdx.x + st];
        __syncthreads();
    }
    float inv = rsqrtf(red[0] / (float)H + EPS);
    for (int i = threadIdx.x; i < H; i += 256) {
        float v = xr[i] * inv * w[i];
        unsigned short hb = f2bf(v);
        oh[(size_t)t * H + i] = hb;
        ol[(size_t)t * H + i] = f2bf(v - bf2f(hb));
    }
}

__global__ void rmsnorm_dual_kernel(const float* __restrict__ x, const float* __restrict__ w,
                                    float* __restrict__ outf, unsigned short* __restrict__ outb) {
    int t = blockIdx.x;
    __shared__ float red[256];
    const float* xr = x + (size_t)t * H;
    float s = 0.f;
    for (int i = threadIdx.x; i < H; i += 256) { float v = xr[i]; s += v * v; }
    red[threadIdx.x] = s;
    __syncthreads();
    for (int st = 128; st > 0; st >>= 1) {
        if (threadIdx.x < st) red[threadIdx.x] += red[threadIdx.x + st];
        __syncthreads();
    }
    float inv = rsqrtf(red[0] / (float)H + EPS);
    for (int i = threadIdx.x; i < H; i += 256) {
        float v = xr[i] * inv * w[i];
        outf[(size_t)t * H + i] = v;
        outb[(size_t)t * H + i] = f2bf(v);
    }
}

// ---------------- one-shot fp32 -> bf16 hi/lo weight split (q,k,v,o) ----------------
__global__ void split_w4(const float* __restrict__ qw, const float* __restrict__ kw,
                         const float* __restrict__ vw, const float* __restrict__ ow,
                         unsigned short* __restrict__ qh, unsigned short* __restrict__ ql,
                         unsigned short* __restrict__ kh, unsigned short* __restrict__ kl,
                         unsigned short* __restrict__ vh, unsigned short* __restrict__ vl,
                         unsigned short* __restrict__ oh, unsigned short* __restrict__ ol) {
    int z = blockIdx.z;
    const float* src;
    unsigned short *dh, *dl;
    int n;
    if (z == 0) { src = qw; dh = qh; dl = ql; n = H * H; }
    else if (z == 1) { src = kw; dh = kh; dl = kl; n = NKV * HD * H; }
    else if (z == 2) { src = vw; dh = vh; dl = vl; n = NKV * HD * H; }
    else { src = ow; dh = oh; dl = ol; n = H * H; }
    int i = (blockIdx.x * 256 + threadIdx.x) * 4;
    if (i >= n) return;
    float4 val = *(const float4*)&src[i];
    float vv[4] = {val.x, val.y, val.z, val.w};
    unsigned short hs[4], ls[4];
#pragma unroll
    for (int j = 0; j < 4; ++j) {
        hs[j] = f2bf(vv[j]);
        ls[j] = f2bf(vv[j] - bf2f(hs[j]));
    }
    uint2 hp, lp;
    hp.x = (unsigned)hs[0] | ((unsigned)hs[1] << 16);
    hp.y = (unsigned)hs[2] | ((unsigned)hs[3] << 16);
    lp.x = (unsigned)ls[0] | ((unsigned)ls[1] << 16);
    lp.y = (unsigned)ls[2] | ((unsigned)ls[3] << 16);
    *(uint2*)&dh[i] = hp;
    *(uint2*)&dl[i] = lp;
}

// ---------------- transpose + fp32->bf16: W (K x N) -> Wt (N x K) ----------------
__global__ __launch_bounds__(256) void transpose_cvt(const float* __restrict__ W,
                                                     unsigned short* __restrict__ Wt, int K,
                                                     int N, int eoff) {
    int zl = blockIdx.z;
    const float* src = W + (size_t)(eoff + zl) * K * N;
    unsigned short* dst = Wt + (size_t)zl * K * N;
    int k0 = blockIdx.y * 64, n0 = blockIdx.x * 64;
    __shared__ unsigned short Ls[64][70];
    int tid = threadIdx.x;
    int nn = (tid & 15) * 4, kr = tid >> 4;
#pragma unroll
    for (int p = 0; p < 4; ++p) {
        int k = kr + p * 16;
        float4 v = *(const float4*)&src[(size_t)(k0 + k) * N + n0 + nn];
        Ls[k][nn] = f2bf(v.x);
        Ls[k][nn + 1] = f2bf(v.y);
        Ls[k][nn + 2] = f2bf(v.z);
        Ls[k][nn + 3] = f2bf(v.w);
    }
    __syncthreads();
    int n = tid >> 2, kq = (tid & 3) * 16;
    U16S o;
#pragma unroll
    for (int j = 0; j < 16; ++j) o.s[j] = Ls[kq + j][n];
    unsigned short* drow = dst + (size_t)(n0 + n) * K + k0 + kq;
    *(uint4*)drow = o.q[0];
    *(uint4*)(drow + 8) = o.q[1];
}

// ---------------- V -> V^T bf16 hi/lo: vb [T][NKV*HD] -> VT [NKV*HD][T] ----------------
__global__ __launch_bounds__(256) void vt_split(const float* __restrict__ vb,
                                                unsigned short* __restrict__ VTh,
                                                unsigned short* __restrict__ VTl) {
    int t0 = blockIdx.x * 64, c0 = blockIdx.y * 64;
    __shared__ unsigned short Hs[64][70], Lsh[64][70];
    int tid = threadIdx.x;
    int nn = (tid & 15) * 4, kr = tid >> 4;
#pragma unroll
    for (int p = 0; p < 4; ++p) {
        int t = kr + p * 16;
        float4 v = *(const float4*)&vb[(size_t)(t0 + t) * (NKV * HD) + c0 + nn];
        float vv[4] = {v.x, v.y, v.z, v.w};
#pragma unroll
        for (int j = 0; j < 4; ++j) {
            unsigned short hb = f2bf(vv[j]);
            Hs[t][nn + j] = hb;
            Lsh[t][nn + j] = f2bf(vv[j] - bf2f(hb));
        }
    }
    __syncthreads();
    int n = tid >> 2, kq = (tid & 3) * 16;
    U16S oh, ol;
#pragma unroll
    for (int j = 0; j < 16; ++j) {
        oh.s[j] = Hs[kq + j][n];
        ol.s[j] = Lsh[kq + j][n];
    }
    size_t drow = (size_t)(c0 + n) * T + t0 + kq;
    *(uint4*)&VTh[drow] = oh.q[0];
    *(uint4*)&VTh[drow + 8] = oh.q[1];
    *(uint4*)&VTl[drow] = ol.q[0];
    *(uint4*)&VTl[drow + 8] = ol.q[1];
}

// ---------------- router logits: per-token dot products ----
__global__ __launch_bounds__(256) void router_logits_kernel(const float* __restrict__ x,
                                                            const float* __restrict__ W,
                                                            float* __restrict__ logits) {
    int t = blockIdx.x;
    __shared__ float xs[H];
    int tid = threadIdx.x;
    *(float4*)&xs[tid * 4] = *(const float4*)&x[(size_t)t * H + tid * 4];
    __syncthreads();
    int e = tid >> 3, p = tid & 7;
    const float* wr = W + (size_t)e * H;
    float s = 0.f;
#pragma unroll
    for (int i = 0; i < 32; ++i) {
        int k = i * 32 + p * 4;
        float4 wv = *(const float4*)&wr[k];
        float4 xv = *(const float4*)&xs[k];
        s += wv.x * xv.x + wv.y * xv.y + wv.z * xv.z + wv.w * xv.w;
    }
#pragma unroll
    for (int off = 1; off < 8; off <<= 1) s += __shfl_xor(s, off);
    if (p == 0) logits[(size_t)t * NE + e] = s;
}

// ---------------- compensated bf16 GEMM, reg-staged prefetch + padded LDS ------------
// Tile 128m x 64n, BK=64 as 2x32 chunks. Fused QKV (W selected by n0).
__global__ __launch_bounds__(256) void gemm3_qkv(
    const unsigned short* __restrict__ Xh, const unsigned short* __restrict__ Xl,
    const unsigned short* __restrict__ Wqh, const unsigned short* __restrict__ Wql,
    const unsigned short* __restrict__ Wkh, const unsigned short* __restrict__ Wkl,
    const unsigned short* __restrict__ Wvh, const unsigned short* __restrict__ Wvl,
    float* __restrict__ qo, float* __restrict__ ko, float* __restrict__ vo) {
    __shared__ __attribute__((aligned(16))) short Ahs[2][128][KP], Als[2][128][KP];
    __shared__ __attribute__((aligned(16))) short Bhs[2][64][KP], Bls[2][64][KP];
    int tid = threadIdx.x;
    int m0 = blockIdx.y * 128;
    int n0 = blockIdx.x * 64;
    const unsigned short *Wh, *Wl;
    float* O;
    int ldo, nc0;
    if (n0 < 1024) { nc0 = n0; Wh = Wqh; Wl = Wql; O = qo; ldo = H; }
    else if (n0 < 1536) { nc0 = n0 - 1024; Wh = Wkh; Wl = Wkl; O = ko; ldo = NKV * HD; }
    else { nc0 = n0 - 1536; Wh = Wvh; Wl = Wvl; O = vo; ldo = NKV * HD; }
    int wave = tid >> 6, lane = tid & 63;
    int lr = lane & 15, lq = lane >> 4;
    int wm = (wave >> 1) * 64, wn = (wave & 1) * 32;
    int srow = lane >> 2, skb = (lane & 3) * 8;
    const unsigned short *ah_p[2], *al_p[2];
#pragma unroll
    for (int p = 0; p < 2; ++p) {
        int m = m0 + wave * 32 + p * 16 + srow;
        ah_p[p] = Xh + (size_t)m * H + skb;
        al_p[p] = Xl + (size_t)m * H + skb;
    }
    int bn = nc0 + wave * 16 + srow;
    const unsigned short* bh_p = Wh + (size_t)bn * H + skb;
    const unsigned short* bl_p = Wl + (size_t)bn * H + skb;
    f32x4 acc[4][2];
#pragma unroll
    for (int i = 0; i < 4; ++i)
#pragma unroll
        for (int j = 0; j < 2; ++j) acc[i][j] = (f32x4){0.f, 0.f, 0.f, 0.f};
    uint4 rah0, rah1, rah2, rah3, ral0, ral1, ral2, ral3, rbh0, rbh1, rbl0, rbl1;
#define LOADQ(K0)                                              \
    {                                                          \
        rah0 = *(const uint4*)(ah_p[0] + (K0));                \
        rah1 = *(const uint4*)(ah_p[1] + (K0));                \
        rah2 = *(const uint4*)(ah_p[0] + (K0) + 32);           \
        rah3 = *(const uint4*)(ah_p[1] + (K0) + 32);           \
        ral0 = *(const uint4*)(al_p[0] + (K0));                \
        ral1 = *(const uint4*)(al_p[1] + (K0));                \
        ral2 = *(const uint4*)(al_p[0] + (K0) + 32);           \
        ral3 = *(const uint4*)(al_p[1] + (K0) + 32);           \
        rbh0 = *(const uint4*)(bh_p + (K0));                   \
        rbh1 = *(const uint4*)(bh_p + (K0) + 32);              \
        rbl0 = *(const uint4*)(bl_p + (K0));                   \
        rbl1 = *(const uint4*)(bl_p + (K0) + 32);              \
    }
    LOADQ(0);
    for (int k0 = 0; k0 < H; k0 += 64) {
        __syncthreads();  // previous iteration's LDS reads done
        *(uint4*)&Ahs[0][wave * 32 + srow][skb] = rah0;
        *(uint4*)&Ahs[0][wave * 32 + 16 + srow][skb] = rah1;
        *(uint4*)&Ahs[1][wave * 32 + srow][skb] = rah2;
        *(uint4*)&Ahs[1][wave * 32 + 16 + srow][skb] = rah3;
        *(uint4*)&Als[0][wave * 32 + srow][skb] = ral0;
        *(uint4*)&Als[0][wave * 32 + 16 + srow][skb] = ral1;
        *(uint4*)&Als[1][wave * 32 + srow][skb] = ral2;
        *(uint4*)&Als[1][wave * 32 + 16 + srow][skb] = ral3;
        *(uint4*)&Bhs[0][wave * 16 + srow][skb] = rbh0;
        *(uint4*)&Bhs[1][wave * 16 + srow][skb] = rbh1;
        *(uint4*)&Bls[0][wave * 16 + srow][skb] = rbl0;
        *(uint4*)&Bls[1][wave * 16 + srow][skb] = rbl1;
        __syncthreads();
        if (k0 + 64 < H) LOADQ(k0 + 64);  // prefetch next tile under compute
#pragma unroll
        for (int c = 0; c < 2; ++c) {
            bf16x8 a_h[4], a_l[4], b_h[2], b_l[2];
#pragma unroll
            for (int mt = 0; mt < 4; ++mt) {
                a_h[mt] = *(const bf16x8*)&Ahs[c][wm + mt * 16 + lr][lq * 8];
                a_l[mt] = *(const bf16x8*)&Als[c][wm + mt * 16 + lr][lq * 8];
            }
#pragma unroll
            for (int nt = 0; nt < 2; ++nt) {
                b_h[nt] = *(const bf16x8*)&Bhs[c][wn + nt * 16 + lr][lq * 8];
                b_l[nt] = *(const bf16x8*)&Bls[c][wn + nt * 16 + lr][lq * 8];
            }
#pragma unroll
            for (int mt = 0; mt < 4; ++mt)
#pragma unroll
                for (int nt = 0; nt < 2; ++nt) {
                    acc[mt][nt] = MFMA16(a_h[mt], b_h[nt], acc[mt][nt]);
                    acc[mt][nt] = MFMA16(a_h[mt], b_l[nt], acc[mt][nt]);
                    acc[mt][nt] = MFMA16(a_l[mt], b_h[nt], acc[mt][nt]);
                }
        }
    }
#undef LOADQ
#pragma unroll
    for (int mt = 0; mt < 4; ++mt)
#pragma unroll
        for (int nt = 0; nt < 2; ++nt)
#pragma unroll
            for (int p = 0; p < 4; ++p) {
                int m = m0 + wm + mt * 16 + lq * 4 + p;
                int col = nc0 + wn + nt * 16 + lr;
                O[(size_t)m * ldo + col] = acc[mt][nt][p];
            }
}

// Same structure, single weight, residual add (o-projection).
__global__ __launch_bounds__(256) void gemm3_res(
    const unsigned short* __restrict__ Agh, const unsigned short* __restrict__ Agl,
    const unsigned short* __restrict__ Wh, const unsigned short* __restrict__ Wl,
    const float* __restrict__ res, float* __restrict__ O) {
    __shared__ __attribute__((aligned(16))) short Ahs[2][128][KP], Als[2][128][KP];
    __shared__ __attribute__((aligned(16))) short Bhs[2][64][KP], Bls[2][64][KP];
    int tid = threadIdx.x;
    int m0 = blockIdx.y * 128;
    int n0 = blockIdx.x * 64;
    int wave = tid >> 6, lane = tid & 63;
    int lr = lane & 15, lq = lane >> 4;
    int wm = (wave >> 1) * 64, wn = (wave & 1) * 32;
    int srow = lane >> 2, skb = (lane & 3) * 8;
    const unsigned short *ah_p[2], *al_p[2];
#pragma unroll
    for (int p = 0; p < 2; ++p) {
        int m = m0 + wave * 32 + p * 16 + srow;
        ah_p[p] = Agh + (size_t)m * H + skb;
        al_p[p] = Agl + (size_t)m * H + skb;
    }
    int bn = n0 + wave * 16 + srow;
    const unsigned short* bh_p = Wh + (size_t)bn * H + skb;
    const unsigned short* bl_p = Wl + (size_t)bn * H + skb;
    f32x4 acc[4][2];
#pragma unroll
    for (int i = 0; i < 4; ++i)
#pragma unroll
        for (int j = 0; j < 2; ++j) acc[i][j] = (f32x4){0.f, 0.f, 0.f, 0.f};
    uint4 rah0, rah1, rah2, rah3, ral0, ral1, ral2, ral3, rbh0, rbh1, rbl0, rbl1;
#define LOADR(K0)                                              \
    {                                                          \
        rah0 = *(const uint4*)(ah_p[0] + (K0));                \
        rah1 = *(const uint4*)(ah_p[1] + (K0));                \
        rah2 = *(const uint4*)(ah_p[0] + (K0) + 32);           \
        rah3 = *(const uint4*)(ah_p[1] + (K0) + 32);           \
        ral0 = *(const uint4*)(al_p[0] + (K0));                \
        ral1 = *(const uint4*)(al_p[1] + (K0));                \
        ral2 = *(const uint4*)(al_p[0] + (K0) + 32);           \
        ral3 = *(const uint4*)(al_p[1] + (K0) + 32);           \
        rbh0 = *(const uint4*)(bh_p + (K0));                   \
        rbh1 = *(const uint4*)(bh_p + (K0) + 32);              \
        rbl0 = *(const uint4*)(bl_p + (K0));                   \
        rbl1 = *(const uint4*)(bl_p + (K0) + 32);              \
    }
    LOADR(0);
    for (int k0 = 0; k0 < H; k0 += 64) {
        __syncthreads();
        *(uint4*)&Ahs[0][wave * 32 + srow][skb] = rah0;
        *(uint4*)&Ahs[0][wave * 32 + 16 + srow][skb] = rah1;
        *(uint4*)&Ahs[1][wave * 32 + srow][skb] = rah2;
        *(uint4*)&Ahs[1][wave * 32 + 16 + srow][skb] = rah3;
        *(uint4*)&Als[0][wave * 32 + srow][skb] = ral0;
        *(uint4*)&Als[0][wave * 32 + 16 + srow][skb] = ral1;
        *(uint4*)&Als[1][wave * 32 + srow][skb] = ral2;
        *(uint4*)&Als[1][wave * 32 + 16 + srow][skb] = ral3;
        *(uint4*)&Bhs[0][wave * 16 + srow][skb] = rbh0;
        *(uint4*)&Bhs[1][wave * 16 + srow][skb] = rbh1;
        *(uint4*)&Bls[0][wave * 16 + srow][skb] = rbl0;
        *(uint4*)&Bls[1][wave * 16 + srow][skb] = rbl1;
        __syncthreads();
        if (k0 + 64 < H) LOADR(k0 + 64);
#pragma unroll
        for (int c = 0; c < 2; ++c) {
            bf16x8 a_h[4], a_l[4], b_h[2], b_l[2];
#pragma unroll
            for (int mt = 0; mt < 4; ++mt) {
                a_h[mt] = *(const bf16x8*)&Ahs[c][wm + mt * 16 + lr][lq * 8];
                a_l[mt] = *(const bf16x8*)&Als[c][wm + mt * 16 + lr][lq * 8];
            }
#pragma unroll
            for (int nt = 0; nt < 2; ++nt) {
                b_h[nt] = *(const bf16x8*)&Bhs[c][wn + nt * 16 + lr][lq * 8];
                b_l[nt] = *(const bf16x8*)&Bls[c][wn + nt * 16 + lr][lq * 8];
            }
#pragma unroll
            for (int mt = 0; mt < 4; ++mt)
#pragma unroll
                for (int nt = 0; nt < 2; ++nt) {
                    acc[mt][nt] = MFMA16(a_h[mt], b_h[nt], acc[mt][nt]);
                    acc[mt][nt] = MFMA16(a_h[mt], b_l[nt], acc[mt][nt]);
                    acc[mt][nt] = MFMA16(a_l[mt], b_h[nt], acc[mt][nt]);
                }
        }
    }
#undef LOADR
#pragma unroll
    for (int mt = 0; mt < 4; ++mt)
#pragma unroll
        for (int nt = 0; nt < 2; ++nt)
#pragma unroll
            for (int p = 0; p < 4; ++p) {
                int m = m0 + wm + mt * 16 + lq * 4 + p;
                int col = n0 + wn + nt * 16 + lr;
                O[(size_t)m * H + col] = res[(size_t)m * H + col] + acc[mt][nt][p];
            }
}

// ---------------- rope: rotate q (fp32 in-place) and k (-> bf16 hi/lo global) --------
__global__ void rope_kernel(float* __restrict__ q, const float* __restrict__ k,
                            const int* __restrict__ pos, unsigned short* __restrict__ Khg,
                            unsigned short* __restrict__ Klg) {
    int i = blockIdx.x * 256 + threadIdx.x;
    const int totq = T * NH * 64;
    const int tot = totq + T * NKV * 64;
    if (i >= tot) return;
    if (i < totq) {
        int r = i;
        int d = r & 63; r >>= 6;
        int hh = r % NH, t = r / NH;
        float p = (float)pos[t];
        float inv = powf(10000.0f, -(float)d / 64.0f);
        float fr = p * inv;
        float sv, cv;
        sincosf(fr, &sv, &cv);
        size_t bi = ((size_t)t * NH + hh) * HD + d;
        float x1 = q[bi], x2 = q[bi + 64];
        q[bi] = x1 * cv - x2 * sv;
        q[bi + 64] = x2 * cv + x1 * sv;
    } else {
        int r = i - totq;
        int d = r & 63; r >>= 6;
        int hh = r % NKV, t = r / NKV;
        float p = (float)pos[t];
        float inv = powf(10000.0f, -(float)d / 64.0f);
        float fr = p * inv;
        float sv, cv;
        sincosf(fr, &sv, &cv);
        size_t bi = ((size_t)t * NKV + hh) * HD + d;
        float x1 = k[bi], x2 = k[bi + 64];
        float n1 = x1 * cv - x2 * sv;
        float n2 = x2 * cv + x1 * sv;
        unsigned short h1 = f2bf(n1), h2b = f2bf(n2);
        Khg[bi] = h1;
        Khg[bi + 64] = h2b;
        Klg[bi] = f2bf(n1 - bf2f(h1));
        Klg[bi + 64] = f2bf(n2 - bf2f(h2b));
    }
}

// ---------------- flash attention, split-K partials, pre-split bf16 K/V --------------
#define KS_LD 136
#define VS_LD 40
#define PS_LD 34
__global__ __launch_bounds__(256) void attn_split(const float* __restrict__ Q,
                                                  const unsigned short* __restrict__ Khg,
                                                  const unsigned short* __restrict__ Klg,
                                                  const unsigned short* __restrict__ VTh,
                                                  const unsigned short* __restrict__ VTl,
                                                  float* __restrict__ po,
                                                  float* __restrict__ pm,
                                                  float* __restrict__ pl) {
    int h = blockIdx.x;
    int qb = blockIdx.y;
    int sp = blockIdx.z;
    int kvh = h >> 1;  // NH/NKV = 2
    int q0 = qb * 64;
    int kend = q0 + 64;  // causal: keys [0, kend)
    int ks = sp * SPLITK;
    if (ks >= kend) return;  // empty split
    int ke = min(ks + SPLITK, kend);
    __shared__ __attribute__((aligned(16))) short Ksh[32][KS_LD], Ksl[32][KS_LD];
    __shared__ __attribute__((aligned(16))) short Vsh[128][VS_LD], Vsl[128][VS_LD];
    __shared__ short Ph[4][16][PS_LD], Pl[4][16][PS_LD];
    int tid = threadIdx.x;
    int wave = tid >> 6, lane = tid & 63;
    int lr = lane & 15, lq = lane >> 4;
    const float scale = 0.08838834764831845f;  // 1/sqrt(128)

    bf16x8 qh[4], ql[4];
    {
        const float* qrow = Q + (size_t)(q0 + wave * 16 + lr) * H + h * HD;
#pragma unroll
        for (int c = 0; c < 4; ++c) {
            float4 v0 = *(const float4*)(qrow + c * 32 + lq * 8);
            float4 v1 = *(const float4*)(qrow + c * 32 + lq * 8 + 4);
            float vv[8] = {v0.x, v0.y, v0.z, v0.w, v1.x, v1.y, v1.z, v1.w};
#pragma unroll
            for (int j = 0; j < 8; ++j) {
                unsigned short hb = f2bf(vv[j]);
                qh[c][j] = (short)hb;
                ql[c][j] = (short)f2bf(vv[j] - bf2f(hb));
            }
        }
    }
    f32x4 o[8];
#pragma unroll
    for (int nt = 0; nt < 8; ++nt) o[nt] = (f32x4){0.f, 0.f, 0.f, 0.f};
    float m_r[4] = {-1e30f, -1e30f, -1e30f, -1e30f};
    float l_r[4] = {0.f, 0.f, 0.f, 0.f};

    int kts = ks >> 5, kte = ke >> 5;
    int ntw = ((q0 + wave * 16 + 15) >> 5) + 1;  // per-wave causal tile bound (global)

    // staging roles: K by (key, 16-short chunk), V^T by (dim row, 16-short chunk)
    int key_k = tid >> 3, kc = (tid & 7) * 16;
    int d_v = tid >> 1, vc = (tid & 1) * 16;
    const unsigned short* kbase_h = Khg + (size_t)kvh * HD + kc;
    const unsigned short* kbase_l = Klg + (size_t)kvh * HD + kc;
    const unsigned short* vbase_h = VTh + (size_t)(kvh * HD + d_v) * T + vc;
    const unsigned short* vbase_l = VTl + (size_t)(kvh * HD + d_v) * T + vc;

    uint4 kr0, kr1, kr2, kr3, vr0, vr1, vr2, vr3;
#define LOADT(KT)                                                                    \
    {                                                                                \
        size_t koff = (size_t)((KT)*32 + key_k) * (NKV * HD);                        \
        kr0 = *(const uint4*)(kbase_h + koff);                                       \
        kr1 = *(const uint4*)(kbase_h + koff + 8);                                   \
        kr2 = *(const uint4*)(kbase_l + koff);                                       \
        kr3 = *(const uint4*)(kbase_l + koff + 8);                                   \
        int voff = (KT)*32;                                                          \
        vr0 = *(const uint4*)(vbase_h + voff);                                       \
        vr1 = *(const uint4*)(vbase_h + voff + 8);                                   \
        vr2 = *(const uint4*)(vbase_l + voff);                                       \
        vr3 = *(const uint4*)(vbase_l + voff + 8);                                   \
    }

    LOADT(kts);
    for (int kt = kts; kt < kte; ++kt) {
        int k0 = kt * 32;
        __syncthreads();  // previous tile's LDS reads done
        *(uint4*)&Ksh[key_k][kc] = kr0;
        *(uint4*)&Ksh[key_k][kc + 8] = kr1;
        *(uint4*)&Ksl[key_k][kc] = kr2;
        *(uint4*)&Ksl[key_k][kc + 8] = kr3;
        *(uint4*)&Vsh[d_v][vc] = vr0;
        *(uint4*)&Vsh[d_v][vc + 8] = vr1;
        *(uint4*)&Vsl[d_v][vc] = vr2;
        *(uint4*)&Vsl[d_v][vc + 8] = vr3;
        __syncthreads();
        if (kt + 1 < kte) LOADT(kt + 1);  // prefetch next tile under compute
        if (kt < ntw) {
            f32x4 s[2];
            s[0] = (f32x4){0.f, 0.f, 0.f, 0.f};
            s[1] = (f32x4){0.f, 0.f, 0.f, 0.f};
#pragma unroll
            for (int nt = 0; nt < 2; ++nt)
#pragma unroll
                for (int c = 0; c < 4; ++c) {
                    bf16x8 kh = *(const bf16x8*)&Ksh[nt * 16 + lr][c * 32 + lq * 8];
                    bf16x8 kl = *(const bf16x8*)&Ksl[nt * 16 + lr][c * 32 + lq * 8];
                    s[nt] = MFMA16(qh[c], kh, s[nt]);
                    s[nt] = MFMA16(ql[c], kh, s[nt]);
                    s[nt] = MFMA16(qh[c], kl, s[nt]);
                }
            int gr_base = q0 + wave * 16 + lq * 4;
#pragma unroll
            for (int nt = 0; nt < 2; ++nt) {
                int gc = k0 + nt * 16 + lr;
#pragma unroll
                for (int p = 0; p < 4; ++p) {
                    float sv = s[nt][p] * scale;
                    if (gc > gr_base + p) sv = -1e30f;
                    s[nt][p] = sv;
                }
            }
            float alpha[4];
#pragma unroll
            for (int p = 0; p < 4; ++p) {
                float mx = fmaxf(s[0][p], s[1][p]);
#pragma unroll
                for (int off = 1; off < 16; off <<= 1) mx = fmaxf(mx, __shfl_xor(mx, off));
                float mn = fmaxf(m_r[p], mx);
                alpha[p] = __expf(m_r[p] - mn);
                float p0 = __expf(s[0][p] - mn);
                float p1 = __expf(s[1][p] - mn);
                float ps = p0 + p1;
#pragma unroll
                for (int off = 1; off < 16; off <<= 1) ps += __shfl_xor(ps, off);
                l_r[p] = l_r[p] * alpha[p] + ps;
                m_r[p] = mn;
                int r = lq * 4 + p;
                unsigned short h0 = f2bf(p0);
                Ph[wave][r][lr] = (short)h0;
                Pl[wave][r][lr] = (short)f2bf(p0 - bf2f(h0));
                unsigned short h1 = f2bf(p1);
                Ph[wave][r][lr + 16] = (short)h1;
                Pl[wave][r][lr + 16] = (short)f2bf(p1 - bf2f(h1));
            }
            bf16x8 pah = *(const bf16x8*)&Ph[wave][lr][lq * 8];
            bf16x8 pal = *(const bf16x8*)&Pl[wave][lr][lq * 8];
#pragma unroll
            for (int nt = 0; nt < 8; ++nt) {
#pragma unroll
                for (int p = 0; p < 4; ++p) o[nt][p] *= alpha[p];
                bf16x8 vh = *(const bf16x8*)&Vsh[nt * 16 + lr][lq * 8];
                bf16x8 vl = *(const bf16x8*)&Vsl[nt * 16 + lr][lq * 8];
                o[nt] = MFMA16(pah, vh, o[nt]);
                o[nt] = MFMA16(pal, vh, o[nt]);
                o[nt] = MFMA16(pah, vl, o[nt]);
            }
        }
    }
#undef LOADT
    // write un-normalized partials (o, m, l), compact causal slot index
    int pbase = h * NPSLOT + cqb_of(qb) + sp;
    float* porow = po + (size_t)pbase * (64 * 128);
#pragma unroll
    for (int nt = 0; nt < 8; ++nt)
#pragma unroll
        for (int p = 0; p < 4; ++p) {
            int row = wave * 16 + lq * 4 + p;
            porow[row * 128 + nt * 16 + lr] = o[nt][p];
        }
    if (lr == 0) {
#pragma unroll
        for (int p = 0; p < 4; ++p) {
            int row = wave * 16 + lq * 4 + p;
            pm[(size_t)pbase * 64 + row] = m_r[p];
            pl[(size_t)pbase * 64 + row] = l_r[p];
        }
    }
}

// merge split-K partials -> bf16 hi/lo attention output
__global__ __launch_bounds__(256) void attn_merge(const float* __restrict__ po,
                                                  const float* __restrict__ pm,
                                                  const float* __restrict__ pl,
                                                  unsigned short* __restrict__ Oh,
                                                  unsigned short* __restrict__ Ol) {
    int h = blockIdx.x, qb = blockIdx.y;
    int nact = qb / 4 + 1;  // ceil((qb+1)*64 / SPLITK)
    int tid = threadIdx.x;
    int row = tid >> 2;
    int c0 = (tid & 3) * 32;
    int pb = h * NPSLOT + cqb_of(qb);
    float ms[ASPLIT], ws[ASPLIT];
    float mstar = -1e30f;
#pragma unroll
    for (int s = 0; s < ASPLIT; ++s)
        if (s < nact) {
            ms[s] = pm[(size_t)(pb + s) * 64 + row];
            mstar = fmaxf(mstar, ms[s]);
        }
    float lstar = 0.f;
#pragma unroll
    for (int s = 0; s < ASPLIT; ++s)
        if (s < nact) {
            ws[s] = __expf(ms[s] - mstar);
            lstar += ws[s] * pl[(size_t)(pb + s) * 64 + row];
        }
    float linv = 1.f / lstar;
    size_t obase = (size_t)(qb * 64 + row) * H + h * HD + c0;
#pragma unroll
    for (int j = 0; j < 32; j += 4) {
        float acc[4] = {0.f, 0.f, 0.f, 0.f};
#pragma unroll
        for (int s = 0; s < ASPLIT; ++s)
            if (s < nact) {
                float4 v =
                    *(const float4*)&po[(size_t)(pb + s) * (64 * 128) + row * 128 + c0 + j];
                acc[0] += ws[s] * v.x;
                acc[1] += ws[s] * v.y;
                acc[2] += ws[s] * v.z;
                acc[3] += ws[s] * v.w;
            }
#pragma unroll
        for (int q = 0; q < 4; ++q) {
            float v = acc[q] * linv;
            unsigned short hb = f2bf(v);
            Oh[obase + j + q] = hb;
            Ol[obase + j + q] = f2bf(v - bf2f(hb));
        }
    }
}

// ---------------- router ----------------
__global__ void router_kernel(const float* __restrict__ logits, const float* __restrict__ bias,
                              int* __restrict__ topk_idx, float* __restrict__ topkw) {
    int t = blockIdx.x * 256 + threadIdx.x;
    if (t >= T) return;
    float sc[NE], sfc[NE];
    for (int e = 0; e < NE; ++e) {
        float s = 1.f / (1.f + expf(-logits[(size_t)t * NE + e]));
        sc[e] = s;
        sfc[e] = s + bias[e];
    }
    float gs[NG];
    for (int g = 0; g < NG; ++g) {
        float m1 = -1e30f, m2 = -1e30f;
        for (int i = 0; i < 4; ++i) {
            float v = sfc[g * 4 + i];
            if (v > m1) { m2 = m1; m1 = v; }
            else if (v > m2) m2 = v;
        }
        gs[g] = m1 + m2;
    }
    bool gmask[NG];
    for (int g = 0; g < NG; ++g) gmask[g] = false;
    for (int r = 0; r < 4; ++r) {
        int bi = 0; float bv = -1e30f;
        for (int g = 0; g < NG; ++g)
            if (gs[g] > bv) { bv = gs[g]; bi = g; }
        gmask[bi] = true;
        gs[bi] = -1e30f;
    }
    float msfc[NE];
    for (int e = 0; e < NE; ++e) msfc[e] = gmask[e >> 2] ? sfc[e] : 0.f;
    int idx[TOPK]; float w[TOPK]; float wsum = 0.f;
    for (int r = 0; r < TOPK; ++r) {
        int bi = 0; float bv = -1e30f;
        for (int e = 0; e < NE; ++e)
            if (msfc[e] > bv) { bv = msfc[e]; bi = e; }
        idx[r] = bi;
        msfc[bi] = -1e30f;
        w[r] = sc[bi];
        wsum += w[r];
    }
    float inv = RSF / (wsum + 1e-20f);
    for (int r = 0; r < TOPK; ++r) {
        topk_idx[(size_t)t * TOPK + r] = idx[r];
        topkw[(size_t)t * TOPK + r] = w[r] * inv;
    }
}

// fused zero + count + scan + fill (single block)
__global__ void bucket_kernel(const int* __restrict__ topk_idx, int* __restrict__ counts,
                              int* __restrict__ offs, int* __restrict__ tok_of,
                              int* __restrict__ slot_of) {
    __shared__ int cnt[NE], off[NE], fil[NE];
    int tid = threadIdx.x;
    if (tid < NE) { cnt[tid] = 0; fil[tid] = 0; }
    __syncthreads();
    for (int i = tid; i < T * TOPK; i += 256) atomicAdd(&cnt[topk_idx[i]], 1);
    __syncthreads();
    if (tid == 0) {
        int a = 0;
        for (int e = 0; e < NE; ++e) { off[e] = a; a += cnt[e]; }
    }
    __syncthreads();
    if (tid < NE) { counts[tid] = cnt[tid]; offs[tid] = off[tid]; }
    for (int i = tid; i < T * TOPK; i += 256) {
        int e = topk_idx[i];
        int p = off[e] + atomicAdd(&fil[e], 1);
        tok_of[p] = i >> 2;
        slot_of[i] = p;
    }
}

// ---------------- dual up-proj: depth-2 reg-staged prefetch + padded LDS (KP=40) -----
__global__ __launch_bounds__(256) void up_mfma2(
    const unsigned short* __restrict__ Xb, const unsigned short* __restrict__ Gt,
    const unsigned short* __restrict__ Ut, size_t wstride, const int* __restrict__ tok_of,
    const int* __restrict__ offs, const int* __restrict__ counts, int eoff,
    unsigned short* __restrict__ outb, int ldo) {
    int zl = blockIdx.z;
    int e = eoff + zl;
    int cnt = counts ? counts[e] : T;
    int base = offs ? offs[e] : 0;
    int m0 = blockIdx.y * 128;
    if (m0 >= cnt) return;
    int n0 = blockIdx.x * 64;
    const unsigned short* gt = Gt + (size_t)zl * wstride;
    const unsigned short* ut = Ut + (size_t)zl * wstride;
    __shared__ __attribute__((aligned(16))) short As[2][128][KP];
    __shared__ __attribute__((aligned(16))) short Gs[2][64][KP];
    __shared__ __attribute__((aligned(16))) short Us[2][64][KP];
    __shared__ int toks[128];
    int tid = threadIdx.x;
    if (tid < 128) {
        int m = m0 + tid;
        if (m >= cnt) m = cnt - 1;
        toks[tid] = tok_of ? tok_of[base + m] : m;
    }
    __syncthreads();
    int wave = tid >> 6, lane = tid & 63;
    int lr = lane & 15, lq = lane >> 4;
    int wm = (wave >> 1) * 64, wn = (wave & 1) * 32;
    int srow = lane >> 2, skb = (lane & 3) * 8;  // 4 lanes per 32-bf16 row
    const unsigned short* aptr[2];
#pragma unroll
    for (int p = 0; p < 2; ++p)
        aptr[p] = Xb + (size_t)toks[wave * 32 + p * 16 + srow] * H + skb;
    const unsigned short* gptr = gt + (size_t)(n0 + wave * 16 + srow) * H + skb;
    const unsigned short* uptr = ut + (size_t)(n0 + wave * 16 + srow) * H + skb;
    f32x4 ag[4][2], au[4][2];
#pragma unroll
    for (int i = 0; i < 4; ++i)
#pragma unroll
        for (int j = 0; j < 2; ++j) {
            ag[i][j] = (f32x4){0.f, 0.f, 0.f, 0.f};
            au[i][j] = (f32x4){0.f, 0.f, 0.f, 0.f};
        }
    // ping (r*) / pong (s*) register sets, depth-2 prefetch
    uint4 ra00, ra01, ra10, ra11, rg0, rg1, ru0, ru1;
    uint4 sa00, sa01, sa10, sa11, sg0, sg1, su0, su1;
#define LOADUA(K0)                                         \
    {                                                      \
        ra00 = *(const uint4*)(aptr[0] + (K0));            \
        ra01 = *(const uint4*)(aptr[1] + (K0));            \
        ra10 = *(const uint4*)(aptr[0] + (K0) + 32);       \
        ra11 = *(const uint4*)(aptr[1] + (K0) + 32);       \
        rg0 = *(const uint4*)(gptr + (K0));                \
        rg1 = *(const uint4*)(gptr + (K0) + 32);           \
        ru0 = *(const uint4*)(uptr + (K0));                \
        ru1 = *(const uint4*)(uptr + (K0) + 32);           \
    }
#define LOADUB(K0)                                         \
    {                                                      \
        sa00 = *(const uint4*)(aptr[0] + (K0));            \
        sa01 = *(const uint4*)(aptr[1] + (K0));            \
        sa10 = *(const uint4*)(aptr[0] + (K0) + 32);       \
        sa11 = *(const uint4*)(aptr[1] + (K0) + 32);       \
        sg0 = *(const uint4*)(gptr + (K0));                \
        sg1 = *(const uint4*)(gptr + (K0) + 32);           \
        su0 = *(const uint4*)(uptr + (K0));                \
        su1 = *(const uint4*)(uptr + (K0) + 32);           \
    }
#define UPMMA                                                                     \
    {                                                                             \
        _Pragma("unroll") for (int c = 0; c < 2; ++c) {                           \
            bf16x8 a[4], gg[2], uu[2];                                            \
            _Pragma("unroll") for (int mt = 0; mt < 4; ++mt)                      \
                a[mt] = *(const bf16x8*)&As[c][wm + mt * 16 + lr][lq * 8];        \
            _Pragma("unroll") for (int nt = 0; nt < 2; ++nt) {                    \
                gg[nt] = *(const bf16x8*)&Gs[c][wn + nt * 16 + lr][lq * 8];       \
                uu[nt] = *(const bf16x8*)&Us[c][wn + nt * 16 + lr][lq * 8];       \
            }                                                                     \
            _Pragma("unroll") for (int mt = 0; mt < 4; ++mt)                      \
                _Pragma("unroll") for (int nt = 0; nt < 2; ++nt) {                \
                    ag[mt][nt] = MFMA16(a[mt], gg[nt], ag[mt][nt]);               \
                    au[mt][nt] = MFMA16(a[mt], uu[nt], au[mt][nt]);               \
                }                                                                 \
        }                                                                         \
    }
    LOADUA(0);
    LOADUB(64);
    for (int k0 = 0; k0 < H; k0 += 128) {
        // half A: tile k0
        __syncthreads();
        *(uint4*)&As[0][wave * 32 + srow][skb] = ra00;
        *(uint4*)&As[0][wave * 32 + 16 + srow][skb] = ra01;
        *(uint4*)&As[1][wave * 32 + srow][skb] = ra10;
        *(uint4*)&As[1][wave * 32 + 16 + srow][skb] = ra11;
        *(uint4*)&Gs[0][wave * 16 + srow][skb] = rg0;
        *(uint4*)&Gs[1][wave * 16 + srow][skb] = rg1;
        *(uint4*)&Us[0][wave * 16 + srow][skb] = ru0;
        *(uint4*)&Us[1][wave * 16 + srow][skb] = ru1;
        __syncthreads();
        if (k0 + 128 < H) LOADUA(k0 + 128);
        UPMMA;
        // half B: tile k0+64
        __syncthreads();
        *(uint4*)&As[0][wave * 32 + srow][skb] = sa00;
        *(uint4*)&As[0][wave * 32 + 16 + srow][skb] = sa01;
        *(uint4*)&As[1][wave * 32 + srow][skb] = sa10;
        *(uint4*)&As[1][wave * 32 + 16 + srow][skb] = sa11;
        *(uint4*)&Gs[0][wave * 16 + srow][skb] = sg0;
        *(uint4*)&Gs[1][wave * 16 + srow][skb] = sg1;
        *(uint4*)&Us[0][wave * 16 + srow][skb] = su0;
        *(uint4*)&Us[1][wave * 16 + srow][skb] = su1;
        __syncthreads();
        if (k0 + 192 < H) LOADUB(k0 + 192);
        UPMMA;
    }
#undef LOADUA
#undef LOADUB
#undef UPMMA
#pragma unroll
    for (int mt = 0; mt < 4; ++mt)
#pragma unroll
        for (int nt = 0; nt < 2; ++nt)
#pragma unroll
            for (int p = 0; p < 4; ++p) {
                int m = m0 + wm + mt * 16 + lq * 4 + p;
                if (m >= cnt) continue;
                int orow = tok_of ? base + m : m;
                int col = n0 + wn + nt * 16 + lr;
                float gv = ag[mt][nt][p], uv = au[mt][nt][p];
                float sv = gv / (1.f + __expf(-gv)) * uv;
                outb[(size_t)orow * ldo + col] = f2bf(sv);
            }
}

// ---------------- down-proj: depth-2 reg-staged prefetch + padded LDS, fp32 out ------
__global__ __launch_bounds__(256) void down_mfma2(const unsigned short* __restrict__ Ab, int K,
                                                  const unsigned short* __restrict__ Wt,
                                                  size_t wstride, const int* __restrict__ offs,
                                                  const int* __restrict__ counts, int eoff,
                                                  float* __restrict__ Co) {
    int zl = blockIdx.z;
    int e = eoff + zl;
    int cnt = counts ? counts[e] : T;
    int base = offs ? offs[e] : 0;
    int m0 = blockIdx.y * 128;
    if (m0 >= cnt) return;
    int n0 = blockIdx.x * 128;
    const unsigned short* wt = Wt + (size_t)zl * wstride;
    __shared__ __attribute__((aligned(16))) short As[2][128][KP];
    __shared__ __attribute__((aligned(16))) short Bs[2][128][KP];
    int tid = threadIdx.x;
    int wave = tid >> 6, lane = tid & 63;
    int lr = lane & 15, lq = lane >> 4;
    int wm = (wave >> 1) * 64, wn = (wave & 1) * 64;
    int srow = lane >> 2, skb = (lane & 3) * 8;
    const unsigned short* aptr[2];
    const unsigned short* bptr[2];
#pragma unroll
    for (int p = 0; p < 2; ++p) {
        int m = m0 + wave * 32 + p * 16 + srow;
        if (m >= cnt) m = cnt - 1;
        aptr[p] = Ab + (size_t)(base + m) * K + skb;
        bptr[p] = wt + (size_t)(n0 + wave * 32 + p * 16 + srow) * K + skb;
    }
    f32x4 acc[4][4];
#pragma unroll
    for (int i = 0; i < 4; ++i)
#pragma unroll
        for (int j = 0; j < 4; ++j) acc[i][j] = (f32x4){0.f, 0.f, 0.f, 0.f};
    uint4 ra00, ra01, ra10, ra11, rb00, rb01, rb10, rb11;
    uint4 sa00, sa01, sa10, sa11, sb00, sb01, sb10, sb11;
#define LOADDA(K0)                                         \
    {                                                      \
        ra00 = *(const uint4*)(aptr[0] + (K0));            \
        ra01 = *(const uint4*)(aptr[1] + (K0));            \
        ra10 = *(const uint4*)(aptr[0] + (K0) + 32);       \
        ra11 = *(const uint4*)(aptr[1] + (K0) + 32);       \
        rb00 = *(const uint4*)(bptr[0] + (K0));            \
        rb01 = *(const uint4*)(bptr[1] + (K0));            \
        rb10 = *(const uint4*)(bptr[0] + (K0) + 32);       \
        rb11 = *(const uint4*)(bptr[1] + (K0) + 32);       \
    }
#define LOADDB(K0)                                         \
    {                                                      \
        sa00 = *(const uint4*)(aptr[0] + (K0));            \
        sa01 = *(const uint4*)(aptr[1] + (K0));            \
        sa10 = *(const uint4*)(aptr[0] + (K0) + 32);       \
        sa11 = *(const uint4*)(aptr[1] + (K0) + 32);       \
        sb00 = *(const uint4*)(bptr[0] + (K0));            \
        sb01 = *(const uint4*)(bptr[1] + (K0));            \
        sb10 = *(const uint4*)(bptr[0] + (K0) + 32);       \
        sb11 = *(const uint4*)(bptr[1] + (K0) + 32);       \
    }
#define DNMMA                                                                     \
    {                                                                             \
        _Pragma("unroll") for (int c = 0; c < 2; ++c) {                           \
            bf16x8 a[4], b[4];                                                    \
            _Pragma("unroll") for (int mt = 0; mt < 4; ++mt)                      \
                a[mt] = *(const bf16x8*)&As[c][wm + mt * 16 + lr][lq * 8];        \
            _Pragma("unroll") for (int nt = 0; nt < 4; ++nt)                      \
                b[nt] = *(const bf16x8*)&Bs[c][wn + nt * 16 + lr][lq * 8];        \
            _Pragma("unroll") for (int mt = 0; mt < 4; ++mt)                      \
                _Pragma("unroll") for (int nt = 0; nt < 4; ++nt)                  \
                    acc[mt][nt] = MFMA16(a[mt], b[nt], acc[mt][nt]);              \
        }                                                                         \
    }
    LOADDA(0);
    LOADDB(64);
    for (int k0 = 0; k0 < K; k0 += 128) {
        // half A: tile k0
        __syncthreads();
        *(uint4*)&As[0][wave * 32 + srow][skb] = ra00;
        *(uint4*)&As[0][wave * 32 + 16 + srow][skb] = ra01;
        *(uint4*)&As[1][wave * 32 + srow][skb] = ra10;
        *(uint4*)&As[1][wave * 32 + 16 + srow][skb] = ra11;
        *(uint4*)&Bs[0][wave * 32 + srow][skb] = rb00;
        *(uint4*)&Bs[0][wave * 32 + 16 + srow][skb] = rb01;
        *(uint4*)&Bs[1][wave * 32 + srow][skb] = rb10;
        *(uint4*)&Bs[1][wave * 32 + 16 + srow][skb] = rb11;
        __syncthreads();
        if (k0 + 128 < K) LOADDA(k0 + 128);
        DNMMA;
        // half B: tile k0+64
        __syncthreads();
        *(uint4*)&As[0][wave * 32 + srow][skb] = sa00;
        *(uint4*)&As[0][wave * 32 + 16 + srow][skb] = sa01;
        *(uint4*)&As[1][wave * 32 + srow][skb] = sa10;
        *(uint4*)&As[1][wave * 32 + 16 + srow][skb] = sa11;
        *(uint4*)&Bs[0][wave * 32 + srow][skb] = sb00;
        *(uint4*)&Bs[0][wave * 32 + 16 + srow][skb] = sb01;
        *(uint4*)&Bs[1][wave * 32 + srow][skb] = sb10;
        *(uint4*)&Bs[1][wave * 32 + 16 + srow][skb] = sb11;
        __syncthreads();
        if (k0 + 192 < K) LOADDB(k0 + 192);
        DNMMA;
    }
#undef LOADDA
#undef LOADDB
#undef DNMMA
#pragma unroll
    for (int mt = 0; mt < 4; ++mt)
#pragma unroll
        for (int nt = 0; nt < 4; ++nt)
#pragma unroll
            for (int p = 0; p < 4; ++p) {
                int m = m0 + wm + mt * 16 + lq * 4 + p;
                if (m >= cnt) continue;
                int col = n0 + wn + nt * 16 + lr;
                Co[(size_t)(base + m) * H + col] = acc[mt][nt][p];
            }
}

// ---------------- final combine ----------------
__global__ void combine_kernel(const float* __restrict__ o_slot, const int* __restrict__ slot_of,
                               const float* __restrict__ topkw, const float* __restrict__ h2,
                               const float* __restrict__ sharedo, float* __restrict__ out) {
    int t = blockIdx.x;
    int d = threadIdx.x * 4;
    float4 a = *(const float4*)&h2[(size_t)t * H + d];
    float4 b = *(const float4*)&sharedo[(size_t)t * H + d];
    float4 acc = make_float4(a.x + b.x, a.y + b.y, a.z + b.z, a.w + b.w);
#pragma unroll
    for (int r = 0; r < TOPK; ++r) {
        int s = slot_of[t * TOPK + r];
        float w = topkw[t * TOPK + r];
        float4 v = *(const float4*)&o_slot[(size_t)s * H + d];
        acc.x += w * v.x; acc.y += w * v.y; acc.z += w * v.z; acc.w += w * v.w;
    }
    *(float4*)&out[(size_t)t * H + d] = acc;
}

// ---------------- launch ----------------
extern "C" void kernel_launch(void* const* d_in, const int* in_sizes, int n_in,
                              void* d_out, int out_size, void* d_ws, size_t ws_size,
                              hipStream_t stream) {
    const float* hidden = (const float*)d_in[0];
    const int* pos = (const int*)d_in[1];
    const float* ln1w = (const float*)d_in[2];
    const float* ln2w = (const float*)d_in[3];
    const float* q_w = (const float*)d_in[4];
    const float* k_w = (const float*)d_in[5];
    const float* v_w = (const float*)d_in[6];
    const float* o_w = (const float*)d_in[7];
    const float* router_w = (const float*)d_in[8];
    const float* router_b = (const float*)d_in[9];
    const float* eg_w = (const float*)d_in[10];
    const float* eu_w = (const float*)d_in[11];
    const float* ed_w = (const float*)d_in[12];
    const float* sg_w = (const float*)d_in[13];
    const float* su_w = (const float*)d_in[14];
    const float* sd_w = (const float*)d_in[15];
    float* out = (float*)d_out;

    float* f = (float*)d_ws;
    // --- arena region (32 MB): attention-phase buffers, reused for shared-expert weights
    float* xslot = f;   f += (size_t)T * H;          // 4 MB: Xh/Xl; then bf16 K/V for attn
    float* qb = f;      f += (size_t)T * H;          // 4 MB
    float* kb = f;      f += (size_t)T * NKV * HD;   // 2 MB
    float* vb = f;      f += (size_t)T * NKV * HD;   // 2 MB
    float* aoslot = f;  f += (size_t)T * H;          // 4 MB: attn out bf16 hi/lo
    float* ext = f;     f += (size_t)4 * 1024 * 1024;  // 16 MB: split qkv/o weights
    // --- persistent buffers
    float* h2 = f;      f += (size_t)T * H;
    float* h_ln2f = f;  f += (size_t)T * H;
    float* logits = f;  f += (size_t)T * NE;
    float* topkw = f;   f += (size_t)T * TOPK;
    float* o_slot = f;  f += (size_t)T * TOPK * H;   // 16 MB; doubles as attn split po
    float* sharedo = f; f += (size_t)T * H;          // 4 MB
    unsigned short* h_ln2b = (unsigned short*)f;
    unsigned short* abuf = h_ln2b + (size_t)T * H;
    unsigned short* ashared = abuf + (size_t)T * TOPK * MI;
    int* topk_idx = (int*)(ashared + (size_t)T * SI);
    int* counts = topk_idx + T * TOPK;
    int* fills = counts + NE;   // unused (kept for layout stability)
    int* offs = fills + NE;
    int* tok_of = offs + NE;
    int* slot_of = tok_of + T * TOPK;
    (void)fills;

    // big all-expert transposed-weight region at fixed 80 MB offset (ws = 256 MiB per
    // harness poison evidence); 96 MB total. Guarded by ws_size with grouped fallback.
    unsigned short* wT = (unsigned short*)((char*)d_ws + (size_t)80 * 1024 * 1024);
    unsigned short* egTall = wT;                              // 32 MB
    unsigned short* euTall = egTall + (size_t)NE * H * MI;    // 32 MB
    unsigned short* edTall = euTall + (size_t)NE * H * MI;    // 32 MB
    bool big_ws = ws_size >= (size_t)(80 + 96 + 1) * 1024 * 1024;

    // split-weight views in the 16 MB extension (dead until MoE overwrites arena)
    unsigned short* We = (unsigned short*)ext;
    const size_t HH = (size_t)H * H;          // 1M elements
    const size_t KH = (size_t)NKV * HD * H;   // 512K elements
    unsigned short* Wqh = We;
    unsigned short* Wql = Wqh + HH;
    unsigned short* Wkh = Wql + HH;
    unsigned short* Wkl = Wkh + KH;
    unsigned short* Wvh = Wkl + KH;
    unsigned short* Wvl = Wvh + KH;
    unsigned short* Woh = Wvl + KH;
    unsigned short* Wol = Woh + HH;

    unsigned short* Xh = (unsigned short*)xslot;
    unsigned short* Xl = Xh + (size_t)T * H;
    unsigned short* Aoh = (unsigned short*)aoslot;
    unsigned short* Aol = Aoh + (size_t)T * H;

    // bf16 K/V for attention (overlay xslot AFTER gemm3_qkv consumed Xh/Xl)
    unsigned short* Khg = (unsigned short*)xslot;          // [T][NKV*HD]
    unsigned short* Klg = Khg + (size_t)T * NKV * HD;
    unsigned short* VTh = Klg + (size_t)T * NKV * HD;      // [NKV*HD][T]
    unsigned short* VTl = VTh + (size_t)T * NKV * HD;

    // attn split-K partial views (live only between attn_split and attn_merge)
    float* attn_po = o_slot;                 // 320 slots * 64*128 fp32 = 10.5 MB
    float* attn_pm = (float*)abuf;           // 320*64 fp32
    float* attn_pl = attn_pm + (size_t)NH * NPSLOT * 64;

    // arena views (grouped fallback + shared expert)
    unsigned short* arena = (unsigned short*)xslot;
    unsigned short* egT = arena;
    unsigned short* euT = arena + (size_t)16 * H * MI;
    unsigned short* edT = arena;
    unsigned short* sgT = arena;
    unsigned short* suT = arena + (size_t)H * SI;
    unsigned short* sdT = arena;

    dim3 b256(256);

    // one-shot hi/lo splits (weights + ln1 activations)
    split_w4<<<dim3(HH / (256 * 4), 1, 4), b256, 0, stream>>>(q_w, k_w, v_w, o_w, Wqh, Wql,
                                                              Wkh, Wkl, Wvh, Wvl, Woh, Wol);
    rmsnorm_split_kernel<<<T, b256, 0, stream>>>(hidden, ln1w, Xh, Xl);

    gemm3_qkv<<<dim3(32, 8), b256, 0, stream>>>(Xh, Xl, Wqh, Wql, Wkh, Wkl, Wvh, Wvl,
                                                qb, kb, vb);
    {
        int tot = T * NH * 64 + T * NKV * 64;
        rope_kernel<<<(tot + 255) / 256, b256, 0, stream>>>(qb, kb, pos, Khg, Klg);
    }
    vt_split<<<dim3(T / 64, (NKV * HD) / 64), b256, 0, stream>>>(vb, VTh, VTl);
    attn_split<<<dim3(NH, T / 64, ASPLIT), b256, 0, stream>>>(qb, Khg, Klg, VTh, VTl,
                                                              attn_po, attn_pm, attn_pl);
    attn_merge<<<dim3(NH, T / 64), b256, 0, stream>>>(attn_po, attn_pm, attn_pl, Aoh, Aol);
    gemm3_res<<<dim3(16, 8), b256, 0, stream>>>(Aoh, Aol, Woh, Wol, hidden, h2);
    rmsnorm_dual_kernel<<<T, b256, 0, stream>>>(h2, ln2w, h_ln2f, h_ln2b);

    router_logits_kernel<<<T, b256, 0, stream>>>(h_ln2f, router_w, logits);
    router_kernel<<<(T + 255) / 256, b256, 0, stream>>>(logits, router_b, topk_idx, topkw);
    bucket_kernel<<<1, b256, 0, stream>>>(topk_idx, counts, offs, tok_of, slot_of);

    if (big_ws) {
        // ---- MoE, single pass over all 32 experts (full-chip up/down dispatches) ----
        transpose_cvt<<<dim3(MI / 64, H / 64, NE), b256, 0, stream>>>(eg_w, egTall, H, MI, 0);
        transpose_cvt<<<dim3(MI / 64, H / 64, NE), b256, 0, stream>>>(eu_w, euTall, H, MI, 0);
        up_mfma2<<<dim3(MI / 64, 8, NE), b256, 0, stream>>>(
            h_ln2b, egTall, euTall, (size_t)H * MI, tok_of, offs, counts, 0, abuf, MI);
        transpose_cvt<<<dim3(H / 64, MI / 64, NE), b256, 0, stream>>>(ed_w, edTall, MI, H, 0);
        down_mfma2<<<dim3(H / 128, 8, NE), b256, 0, stream>>>(
            abuf, MI, edTall, (size_t)MI * H, offs, counts, 0, o_slot);
    } else {
        // ---- fallback: 2 expert groups of 16 through the 32 MB arena ----
        for (int g = 0; g < 2; ++g) {
            int eo = g * 16;
            transpose_cvt<<<dim3(MI / 64, H / 64, 16), b256, 0, stream>>>(eg_w, egT, H, MI, eo);
            transpose_cvt<<<dim3(MI / 64, H / 64, 16), b256, 0, stream>>>(eu_w, euT, H, MI, eo);
            up_mfma2<<<dim3(MI / 64, 8, 16), b256, 0, stream>>>(
                h_ln2b, egT, euT, (size_t)H * MI, tok_of, offs, counts, eo, abuf, MI);
        }
        for (int g = 0; g < 2; ++g) {
            int eo = g * 16;
            transpose_cvt<<<dim3(H / 64, MI / 64, 16), b256, 0, stream>>>(ed_w, edT, MI, H, eo);
            down_mfma2<<<dim3(H / 128, 8, 16), b256, 0, stream>>>(
                abuf, MI, edT, (size_t)MI * H, offs, counts, eo, o_slot);
        }
    }
    // ---- shared expert (arena; xslot is free after attention) ----
    transpose_cvt<<<dim3(SI / 64, H / 64, 1), b256, 0, stream>>>(sg_w, sgT, H, SI, 0);
    transpose_cvt<<<dim3(SI / 64, H / 64, 1), b256, 0, stream>>>(su_w, suT, H, SI, 0);
    up_mfma2<<<dim3(SI / 64, T / 128, 1), b256, 0, stream>>>(
        h_ln2b, sgT, suT, 0, nullptr, nullptr, nullptr, 0, ashared, SI);
    transpose_cvt<<<dim3(H / 64, SI / 64, 1), b256, 0, stream>>>(sd_w, sdT, SI, H, 0);
    down_mfma2<<<dim3(H / 128, T / 128, 1), b256, 0, stream>>>(
        ashared, SI, sdT, 0, nullptr, nullptr, 0, sharedo);

    combine_kernel<<<T, b256, 0, stream>>>(o_slot, slot_of, topkw, h2, sharedo, out);
}

// Round 9
// 485.099 us; speedup vs baseline: 1.0825x; 1.0825x over previous
//
#include <hip/hip_runtime.h>
#include <math.h>

#define T 1024
#define H 1024
#define NH 8
#define NKV 4
#define HD 128
#define NE 32
#define TOPK 4
#define NG 8
#define MI 512
#define SI 1024
#define RSF 2.5f
#define EPS 1e-6f

// attention split-K params
#define ASPLIT 4
#define SPLITK 256
#define NPSLOT 40  // compact partial slots per head: sum_{qb<16} (qb/4+1)

// padded LDS row stride (shorts) for reg-staged MFMA tiles: 80 B rows, 16 B aligned
#define KP 40

typedef short bf16x8 __attribute__((ext_vector_type(8)));
typedef float f32x4 __attribute__((ext_vector_type(4)));
#define MFMA16(a, b, c) __builtin_amdgcn_mfma_f32_16x16x32_bf16((a), (b), (c), 0, 0, 0)

__device__ inline unsigned short f2bf(float x) {
    unsigned u = __float_as_uint(x);
    u += 0x7fff + ((u >> 16) & 1);  // RNE
    return (unsigned short)(u >> 16);
}
__device__ inline float bf2f(unsigned short h) { return __uint_as_float(((unsigned)h) << 16); }

// compact causal split-slot prefix: C(qb) = sum_{j<qb}(j/4+1)
__device__ __host__ inline int cqb_of(int qb) {
    int a = qb >> 2, r = qb & 3;
    return (a + 1) * (2 * a + r);
}

union U16S {
    unsigned short s[16];
    uint4 q[2];
};

// ---------------- rmsnorm -> bf16 hi/lo split output ----------------
__global__ void rmsnorm_split_kernel(const float* __restrict__ x, const float* __restrict__ w,
                                     unsigned short* __restrict__ oh,
                                     unsigned short* __restrict__ ol) {
    int t = blockIdx.x;
    __shared__ float red[256];
    const float* xr = x + (size_t)t * H;
    float s = 0.f;
    for (int i = threadIdx.x; i < H; i += 256) { float v = xr[i]; s += v * v; }
    red[threadIdx.x] = s;
    __syncthreads();
    for (int st = 128; st > 0; st >>= 1) {
        if (threadIdx.x < st) red[threadIdx.x] += red[threadIdx.x + st];
        __syncthreads();
    }
    float inv = rsqrtf(red[0] / (float)H + EPS);
    for (int i = threadIdx.x; i < H; i += 256) {
        float v = xr[i] * inv * w[i];
        unsigned short hb = f2bf(v);
        oh[(size_t)t * H + i] = hb;
        ol[(size_t)t * H + i] = f2bf(v - bf2f(hb));
    }
}

__global__ void rmsnorm_dual_kernel(const float* __restrict__ x, const float* __restrict__ w,
                                    float* __restrict__ outf, unsigned short* __restrict__ outb) {
    int t = blockIdx.x;
    __shared__ float red[256];
    const float* xr = x + (size_t)t * H;
    float s = 0.f;
    for (int i = threadIdx.x; i < H; i += 256) { float v = xr[i]; s += v * v; }
    red[threadIdx.x] = s;
    __syncthreads();
    for (int st = 128; st > 0; st >>= 1) {
        if (threadIdx.x < st) red[threadIdx.x] += red[threadIdx.x + st];
        __syncthreads();
    }
    float inv = rsqrtf(red[0] / (float)H + EPS);
    for (int i = threadIdx.x; i < H; i += 256) {
        float v = xr[i] * inv * w[i];
        outf[(size_t)t * H + i] = v;
        outb[(size_t)t * H + i] = f2bf(v);
    }
}

// ---------------- one-shot fp32 -> bf16 hi/lo weight split (q,k,v,o) ----------------
__global__ void split_w4(const float* __restrict__ qw, const float* __restrict__ kw,
                         const float* __restrict__ vw, const float* __restrict__ ow,
                         unsigned short* __restrict__ qh, unsigned short* __restrict__ ql,
                         unsigned short* __restrict__ kh, unsigned short* __restrict__ kl,
                         unsigned short* __restrict__ vh, unsigned short* __restrict__ vl,
                         unsigned short* __restrict__ oh, unsigned short* __restrict__ ol) {
    int z = blockIdx.z;
    const float* src;
    unsigned short *dh, *dl;
    int n;
    if (z == 0) { src = qw; dh = qh; dl = ql; n = H * H; }
    else if (z == 1) { src = kw; dh = kh; dl = kl; n = NKV * HD * H; }
    else if (z == 2) { src = vw; dh = vh; dl = vl; n = NKV * HD * H; }
    else { src = ow; dh = oh; dl = ol; n = H * H; }
    int i = (blockIdx.x * 256 + threadIdx.x) * 4;
    if (i >= n) return;
    float4 val = *(const float4*)&src[i];
    float vv[4] = {val.x, val.y, val.z, val.w};
    unsigned short hs[4], ls[4];
#pragma unroll
    for (int j = 0; j < 4; ++j) {
        hs[j] = f2bf(vv[j]);
        ls[j] = f2bf(vv[j] - bf2f(hs[j]));
    }
    uint2 hp, lp;
    hp.x = (unsigned)hs[0] | ((unsigned)hs[1] << 16);
    hp.y = (unsigned)hs[2] | ((unsigned)hs[3] << 16);
    lp.x = (unsigned)ls[0] | ((unsigned)ls[1] << 16);
    lp.y = (unsigned)ls[2] | ((unsigned)ls[3] << 16);
    *(uint2*)&dh[i] = hp;
    *(uint2*)&dl[i] = lp;
}

// ---------------- transpose + fp32->bf16: W (K x N) -> Wt (N x K) ----------------
__global__ __launch_bounds__(256) void transpose_cvt(const float* __restrict__ W,
                                                     unsigned short* __restrict__ Wt, int K,
                                                     int N, int eoff) {
    int zl = blockIdx.z;
    const float* src = W + (size_t)(eoff + zl) * K * N;
    unsigned short* dst = Wt + (size_t)zl * K * N;
    int k0 = blockIdx.y * 64, n0 = blockIdx.x * 64;
    __shared__ unsigned short Ls[64][70];
    int tid = threadIdx.x;
    int nn = (tid & 15) * 4, kr = tid >> 4;
#pragma unroll
    for (int p = 0; p < 4; ++p) {
        int k = kr + p * 16;
        float4 v = *(const float4*)&src[(size_t)(k0 + k) * N + n0 + nn];
        Ls[k][nn] = f2bf(v.x);
        Ls[k][nn + 1] = f2bf(v.y);
        Ls[k][nn + 2] = f2bf(v.z);
        Ls[k][nn + 3] = f2bf(v.w);
    }
    __syncthreads();
    int n = tid >> 2, kq = (tid & 3) * 16;
    U16S o;
#pragma unroll
    for (int j = 0; j < 16; ++j) o.s[j] = Ls[kq + j][n];
    unsigned short* drow = dst + (size_t)(n0 + n) * K + k0 + kq;
    *(uint4*)drow = o.q[0];
    *(uint4*)(drow + 8) = o.q[1];
}

// ---------------- V -> V^T bf16 hi/lo: vb [T][NKV*HD] -> VT [NKV*HD][T] ----------------
__global__ __launch_bounds__(256) void vt_split(const float* __restrict__ vb,
                                                unsigned short* __restrict__ VTh,
                                                unsigned short* __restrict__ VTl) {
    int t0 = blockIdx.x * 64, c0 = blockIdx.y * 64;
    __shared__ unsigned short Hs[64][70], Lsh[64][70];
    int tid = threadIdx.x;
    int nn = (tid & 15) * 4, kr = tid >> 4;
#pragma unroll
    for (int p = 0; p < 4; ++p) {
        int t = kr + p * 16;
        float4 v = *(const float4*)&vb[(size_t)(t0 + t) * (NKV * HD) + c0 + nn];
        float vv[4] = {v.x, v.y, v.z, v.w};
#pragma unroll
        for (int j = 0; j < 4; ++j) {
            unsigned short hb = f2bf(vv[j]);
            Hs[t][nn + j] = hb;
            Lsh[t][nn + j] = f2bf(vv[j] - bf2f(hb));
        }
    }
    __syncthreads();
    int n = tid >> 2, kq = (tid & 3) * 16;
    U16S oh, ol;
#pragma unroll
    for (int j = 0; j < 16; ++j) {
        oh.s[j] = Hs[kq + j][n];
        ol.s[j] = Lsh[kq + j][n];
    }
    size_t drow = (size_t)(c0 + n) * T + t0 + kq;
    *(uint4*)&VTh[drow] = oh.q[0];
    *(uint4*)&VTh[drow + 8] = oh.q[1];
    *(uint4*)&VTl[drow] = ol.q[0];
    *(uint4*)&VTl[drow + 8] = ol.q[1];
}

// ---------------- router logits: per-token dot products ----
__global__ __launch_bounds__(256) void router_logits_kernel(const float* __restrict__ x,
                                                            const float* __restrict__ W,
                                                            float* __restrict__ logits) {
    int t = blockIdx.x;
    __shared__ float xs[H];
    int tid = threadIdx.x;
    *(float4*)&xs[tid * 4] = *(const float4*)&x[(size_t)t * H + tid * 4];
    __syncthreads();
    int e = tid >> 3, p = tid & 7;
    const float* wr = W + (size_t)e * H;
    float s = 0.f;
#pragma unroll
    for (int i = 0; i < 32; ++i) {
        int k = i * 32 + p * 4;
        float4 wv = *(const float4*)&wr[k];
        float4 xv = *(const float4*)&xs[k];
        s += wv.x * xv.x + wv.y * xv.y + wv.z * xv.z + wv.w * xv.w;
    }
#pragma unroll
    for (int off = 1; off < 8; off <<= 1) s += __shfl_xor(s, off);
    if (p == 0) logits[(size_t)t * NE + e] = s;
}

// ---------------- compensated bf16 GEMM, reg-staged prefetch + padded LDS ------------
// Tile 128m x 64n, BK=64 as 2x32 chunks. Fused QKV (W selected by n0).
__global__ __launch_bounds__(256) void gemm3_qkv(
    const unsigned short* __restrict__ Xh, const unsigned short* __restrict__ Xl,
    const unsigned short* __restrict__ Wqh, const unsigned short* __restrict__ Wql,
    const unsigned short* __restrict__ Wkh, const unsigned short* __restrict__ Wkl,
    const unsigned short* __restrict__ Wvh, const unsigned short* __restrict__ Wvl,
    float* __restrict__ qo, float* __restrict__ ko, float* __restrict__ vo) {
    __shared__ __attribute__((aligned(16))) short Ahs[2][128][KP], Als[2][128][KP];
    __shared__ __attribute__((aligned(16))) short Bhs[2][64][KP], Bls[2][64][KP];
    int tid = threadIdx.x;
    int m0 = blockIdx.y * 128;
    int n0 = blockIdx.x * 64;
    const unsigned short *Wh, *Wl;
    float* O;
    int ldo, nc0;
    if (n0 < 1024) { nc0 = n0; Wh = Wqh; Wl = Wql; O = qo; ldo = H; }
    else if (n0 < 1536) { nc0 = n0 - 1024; Wh = Wkh; Wl = Wkl; O = ko; ldo = NKV * HD; }
    else { nc0 = n0 - 1536; Wh = Wvh; Wl = Wvl; O = vo; ldo = NKV * HD; }
    int wave = tid >> 6, lane = tid & 63;
    int lr = lane & 15, lq = lane >> 4;
    int wm = (wave >> 1) * 64, wn = (wave & 1) * 32;
    int srow = lane >> 2, skb = (lane & 3) * 8;
    const unsigned short *ah_p[2], *al_p[2];
#pragma unroll
    for (int p = 0; p < 2; ++p) {
        int m = m0 + wave * 32 + p * 16 + srow;
        ah_p[p] = Xh + (size_t)m * H + skb;
        al_p[p] = Xl + (size_t)m * H + skb;
    }
    int bn = nc0 + wave * 16 + srow;
    const unsigned short* bh_p = Wh + (size_t)bn * H + skb;
    const unsigned short* bl_p = Wl + (size_t)bn * H + skb;
    f32x4 acc[4][2];
#pragma unroll
    for (int i = 0; i < 4; ++i)
#pragma unroll
        for (int j = 0; j < 2; ++j) acc[i][j] = (f32x4){0.f, 0.f, 0.f, 0.f};
    uint4 rah0, rah1, rah2, rah3, ral0, ral1, ral2, ral3, rbh0, rbh1, rbl0, rbl1;
#define LOADQ(K0)                                              \
    {                                                          \
        rah0 = *(const uint4*)(ah_p[0] + (K0));                \
        rah1 = *(const uint4*)(ah_p[1] + (K0));                \
        rah2 = *(const uint4*)(ah_p[0] + (K0) + 32);           \
        rah3 = *(const uint4*)(ah_p[1] + (K0) + 32);           \
        ral0 = *(const uint4*)(al_p[0] + (K0));                \
        ral1 = *(const uint4*)(al_p[1] + (K0));                \
        ral2 = *(const uint4*)(al_p[0] + (K0) + 32);           \
        ral3 = *(const uint4*)(al_p[1] + (K0) + 32);           \
        rbh0 = *(const uint4*)(bh_p + (K0));                   \
        rbh1 = *(const uint4*)(bh_p + (K0) + 32);              \
        rbl0 = *(const uint4*)(bl_p + (K0));                   \
        rbl1 = *(const uint4*)(bl_p + (K0) + 32);              \
    }
    LOADQ(0);
    for (int k0 = 0; k0 < H; k0 += 64) {
        __syncthreads();  // previous iteration's LDS reads done
        *(uint4*)&Ahs[0][wave * 32 + srow][skb] = rah0;
        *(uint4*)&Ahs[0][wave * 32 + 16 + srow][skb] = rah1;
        *(uint4*)&Ahs[1][wave * 32 + srow][skb] = rah2;
        *(uint4*)&Ahs[1][wave * 32 + 16 + srow][skb] = rah3;
        *(uint4*)&Als[0][wave * 32 + srow][skb] = ral0;
        *(uint4*)&Als[0][wave * 32 + 16 + srow][skb] = ral1;
        *(uint4*)&Als[1][wave * 32 + srow][skb] = ral2;
        *(uint4*)&Als[1][wave * 32 + 16 + srow][skb] = ral3;
        *(uint4*)&Bhs[0][wave * 16 + srow][skb] = rbh0;
        *(uint4*)&Bhs[1][wave * 16 + srow][skb] = rbh1;
        *(uint4*)&Bls[0][wave * 16 + srow][skb] = rbl0;
        *(uint4*)&Bls[1][wave * 16 + srow][skb] = rbl1;
        __syncthreads();
        if (k0 + 64 < H) LOADQ(k0 + 64);  // prefetch next tile under compute
#pragma unroll
        for (int c = 0; c < 2; ++c) {
            bf16x8 a_h[4], a_l[4], b_h[2], b_l[2];
#pragma unroll
            for (int mt = 0; mt < 4; ++mt) {
                a_h[mt] = *(const bf16x8*)&Ahs[c][wm + mt * 16 + lr][lq * 8];
                a_l[mt] = *(const bf16x8*)&Als[c][wm + mt * 16 + lr][lq * 8];
            }
#pragma unroll
            for (int nt = 0; nt < 2; ++nt) {
                b_h[nt] = *(const bf16x8*)&Bhs[c][wn + nt * 16 + lr][lq * 8];
                b_l[nt] = *(const bf16x8*)&Bls[c][wn + nt * 16 + lr][lq * 8];
            }
#pragma unroll
            for (int mt = 0; mt < 4; ++mt)
#pragma unroll
                for (int nt = 0; nt < 2; ++nt) {
                    acc[mt][nt] = MFMA16(a_h[mt], b_h[nt], acc[mt][nt]);
                    acc[mt][nt] = MFMA16(a_h[mt], b_l[nt], acc[mt][nt]);
                    acc[mt][nt] = MFMA16(a_l[mt], b_h[nt], acc[mt][nt]);
                }
        }
    }
#undef LOADQ
#pragma unroll
    for (int mt = 0; mt < 4; ++mt)
#pragma unroll
        for (int nt = 0; nt < 2; ++nt)
#pragma unroll
            for (int p = 0; p < 4; ++p) {
                int m = m0 + wm + mt * 16 + lq * 4 + p;
                int col = nc0 + wn + nt * 16 + lr;
                O[(size_t)m * ldo + col] = acc[mt][nt][p];
            }
}

// Same structure, single weight, residual add (o-projection).
__global__ __launch_bounds__(256) void gemm3_res(
    const unsigned short* __restrict__ Agh, const unsigned short* __restrict__ Agl,
    const unsigned short* __restrict__ Wh, const unsigned short* __restrict__ Wl,
    const float* __restrict__ res, float* __restrict__ O) {
    __shared__ __attribute__((aligned(16))) short Ahs[2][128][KP], Als[2][128][KP];
    __shared__ __attribute__((aligned(16))) short Bhs[2][64][KP], Bls[2][64][KP];
    int tid = threadIdx.x;
    int m0 = blockIdx.y * 128;
    int n0 = blockIdx.x * 64;
    int wave = tid >> 6, lane = tid & 63;
    int lr = lane & 15, lq = lane >> 4;
    int wm = (wave >> 1) * 64, wn = (wave & 1) * 32;
    int srow = lane >> 2, skb = (lane & 3) * 8;
    const unsigned short *ah_p[2], *al_p[2];
#pragma unroll
    for (int p = 0; p < 2; ++p) {
        int m = m0 + wave * 32 + p * 16 + srow;
        ah_p[p] = Agh + (size_t)m * H + skb;
        al_p[p] = Agl + (size_t)m * H + skb;
    }
    int bn = n0 + wave * 16 + srow;
    const unsigned short* bh_p = Wh + (size_t)bn * H + skb;
    const unsigned short* bl_p = Wl + (size_t)bn * H + skb;
    f32x4 acc[4][2];
#pragma unroll
    for (int i = 0; i < 4; ++i)
#pragma unroll
        for (int j = 0; j < 2; ++j) acc[i][j] = (f32x4){0.f, 0.f, 0.f, 0.f};
    uint4 rah0, rah1, rah2, rah3, ral0, ral1, ral2, ral3, rbh0, rbh1, rbl0, rbl1;
#define LOADR(K0)                                              \
    {                                                          \
        rah0 = *(const uint4*)(ah_p[0] + (K0));                \
        rah1 = *(const uint4*)(ah_p[1] + (K0));                \
        rah2 = *(const uint4*)(ah_p[0] + (K0) + 32);           \
        rah3 = *(const uint4*)(ah_p[1] + (K0) + 32);           \
        ral0 = *(const uint4*)(al_p[0] + (K0));                \
        ral1 = *(const uint4*)(al_p[1] + (K0));                \
        ral2 = *(const uint4*)(al_p[0] + (K0) + 32);           \
        ral3 = *(const uint4*)(al_p[1] + (K0) + 32);           \
        rbh0 = *(const uint4*)(bh_p + (K0));                   \
        rbh1 = *(const uint4*)(bh_p + (K0) + 32);              \
        rbl0 = *(const uint4*)(bl_p + (K0));                   \
        rbl1 = *(const uint4*)(bl_p + (K0) + 32);              \
    }
    LOADR(0);
    for (int k0 = 0; k0 < H; k0 += 64) {
        __syncthreads();
        *(uint4*)&Ahs[0][wave * 32 + srow][skb] = rah0;
        *(uint4*)&Ahs[0][wave * 32 + 16 + srow][skb] = rah1;
        *(uint4*)&Ahs[1][wave * 32 + srow][skb] = rah2;
        *(uint4*)&Ahs[1][wave * 32 + 16 + srow][skb] = rah3;
        *(uint4*)&Als[0][wave * 32 + srow][skb] = ral0;
        *(uint4*)&Als[0][wave * 32 + 16 + srow][skb] = ral1;
        *(uint4*)&Als[1][wave * 32 + srow][skb] = ral2;
        *(uint4*)&Als[1][wave * 32 + 16 + srow][skb] = ral3;
        *(uint4*)&Bhs[0][wave * 16 + srow][skb] = rbh0;
        *(uint4*)&Bhs[1][wave * 16 + srow][skb] = rbh1;
        *(uint4*)&Bls[0][wave * 16 + srow][skb] = rbl0;
        *(uint4*)&Bls[1][wave * 16 + srow][skb] = rbl1;
        __syncthreads();
        if (k0 + 64 < H) LOADR(k0 + 64);
#pragma unroll
        for (int c = 0; c < 2; ++c) {
            bf16x8 a_h[4], a_l[4], b_h[2], b_l[2];
#pragma unroll
            for (int mt = 0; mt < 4; ++mt) {
                a_h[mt] = *(const bf16x8*)&Ahs[c][wm + mt * 16 + lr][lq * 8];
                a_l[mt] = *(const bf16x8*)&Als[c][wm + mt * 16 + lr][lq * 8];
            }
#pragma unroll
            for (int nt = 0; nt < 2; ++nt) {
                b_h[nt] = *(const bf16x8*)&Bhs[c][wn + nt * 16 + lr][lq * 8];
                b_l[nt] = *(const bf16x8*)&Bls[c][wn + nt * 16 + lr][lq * 8];
            }
#pragma unroll
            for (int mt = 0; mt < 4; ++mt)
#pragma unroll
                for (int nt = 0; nt < 2; ++nt) {
                    acc[mt][nt] = MFMA16(a_h[mt], b_h[nt], acc[mt][nt]);
                    acc[mt][nt] = MFMA16(a_h[mt], b_l[nt], acc[mt][nt]);
                    acc[mt][nt] = MFMA16(a_l[mt], b_h[nt], acc[mt][nt]);
                }
        }
    }
#undef LOADR
#pragma unroll
    for (int mt = 0; mt < 4; ++mt)
#pragma unroll
        for (int nt = 0; nt < 2; ++nt)
#pragma unroll
            for (int p = 0; p < 4; ++p) {
                int m = m0 + wm + mt * 16 + lq * 4 + p;
                int col = n0 + wn + nt * 16 + lr;
                O[(size_t)m * H + col] = res[(size_t)m * H + col] + acc[mt][nt][p];
            }
}

// ---------------- rope: rotate q (fp32 in-place) and k (-> bf16 hi/lo global) --------
__global__ void rope_kernel(float* __restrict__ q, const float* __restrict__ k,
                            const int* __restrict__ pos, unsigned short* __restrict__ Khg,
                            unsigned short* __restrict__ Klg) {
    int i = blockIdx.x * 256 + threadIdx.x;
    const int totq = T * NH * 64;
    const int tot = totq + T * NKV * 64;
    if (i >= tot) return;
    if (i < totq) {
        int r = i;
        int d = r & 63; r >>= 6;
        int hh = r % NH, t = r / NH;
        float p = (float)pos[t];
        float inv = powf(10000.0f, -(float)d / 64.0f);
        float fr = p * inv;
        float sv, cv;
        sincosf(fr, &sv, &cv);
        size_t bi = ((size_t)t * NH + hh) * HD + d;
        float x1 = q[bi], x2 = q[bi + 64];
        q[bi] = x1 * cv - x2 * sv;
        q[bi + 64] = x2 * cv + x1 * sv;
    } else {
        int r = i - totq;
        int d = r & 63; r >>= 6;
        int hh = r % NKV, t = r / NKV;
        float p = (float)pos[t];
        float inv = powf(10000.0f, -(float)d / 64.0f);
        float fr = p * inv;
        float sv, cv;
        sincosf(fr, &sv, &cv);
        size_t bi = ((size_t)t * NKV + hh) * HD + d;
        float x1 = k[bi], x2 = k[bi + 64];
        float n1 = x1 * cv - x2 * sv;
        float n2 = x2 * cv + x1 * sv;
        unsigned short h1 = f2bf(n1), h2b = f2bf(n2);
        Khg[bi] = h1;
        Khg[bi + 64] = h2b;
        Klg[bi] = f2bf(n1 - bf2f(h1));
        Klg[bi + 64] = f2bf(n2 - bf2f(h2b));
    }
}

// ---------------- flash attention, split-K partials, pre-split bf16 K/V --------------
#define KS_LD 136
#define VS_LD 40
#define PS_LD 34
__global__ __launch_bounds__(256) void attn_split(const float* __restrict__ Q,
                                                  const unsigned short* __restrict__ Khg,
                                                  const unsigned short* __restrict__ Klg,
                                                  const unsigned short* __restrict__ VTh,
                                                  const unsigned short* __restrict__ VTl,
                                                  float* __restrict__ po,
                                                  float* __restrict__ pm,
                                                  float* __restrict__ pl) {
    int h = blockIdx.x;
    int qb = blockIdx.y;
    int sp = blockIdx.z;
    int kvh = h >> 1;  // NH/NKV = 2
    int q0 = qb * 64;
    int kend = q0 + 64;  // causal: keys [0, kend)
    int ks = sp * SPLITK;
    if (ks >= kend) return;  // empty split
    int ke = min(ks + SPLITK, kend);
    __shared__ __attribute__((aligned(16))) short Ksh[32][KS_LD], Ksl[32][KS_LD];
    __shared__ __attribute__((aligned(16))) short Vsh[128][VS_LD], Vsl[128][VS_LD];
    __shared__ short Ph[4][16][PS_LD], Pl[4][16][PS_LD];
    int tid = threadIdx.x;
    int wave = tid >> 6, lane = tid & 63;
    int lr = lane & 15, lq = lane >> 4;
    const float scale = 0.08838834764831845f;  // 1/sqrt(128)

    bf16x8 qh[4], ql[4];
    {
        const float* qrow = Q + (size_t)(q0 + wave * 16 + lr) * H + h * HD;
#pragma unroll
        for (int c = 0; c < 4; ++c) {
            float4 v0 = *(const float4*)(qrow + c * 32 + lq * 8);
            float4 v1 = *(const float4*)(qrow + c * 32 + lq * 8 + 4);
            float vv[8] = {v0.x, v0.y, v0.z, v0.w, v1.x, v1.y, v1.z, v1.w};
#pragma unroll
            for (int j = 0; j < 8; ++j) {
                unsigned short hb = f2bf(vv[j]);
                qh[c][j] = (short)hb;
                ql[c][j] = (short)f2bf(vv[j] - bf2f(hb));
            }
        }
    }
    f32x4 o[8];
#pragma unroll
    for (int nt = 0; nt < 8; ++nt) o[nt] = (f32x4){0.f, 0.f, 0.f, 0.f};
    float m_r[4] = {-1e30f, -1e30f, -1e30f, -1e30f};
    float l_r[4] = {0.f, 0.f, 0.f, 0.f};

    int kts = ks >> 5, kte = ke >> 5;
    int ntw = ((q0 + wave * 16 + 15) >> 5) + 1;  // per-wave causal tile bound (global)

    // staging roles: K by (key, 16-short chunk), V^T by (dim row, 16-short chunk)
    int key_k = tid >> 3, kc = (tid & 7) * 16;
    int d_v = tid >> 1, vc = (tid & 1) * 16;
    const unsigned short* kbase_h = Khg + (size_t)kvh * HD + kc;
    const unsigned short* kbase_l = Klg + (size_t)kvh * HD + kc;
    const unsigned short* vbase_h = VTh + (size_t)(kvh * HD + d_v) * T + vc;
    const unsigned short* vbase_l = VTl + (size_t)(kvh * HD + d_v) * T + vc;

    uint4 kr0, kr1, kr2, kr3, vr0, vr1, vr2, vr3;
#define LOADT(KT)                                                                    \
    {                                                                                \
        size_t koff = (size_t)((KT)*32 + key_k) * (NKV * HD);                        \
        kr0 = *(const uint4*)(kbase_h + koff);                                       \
        kr1 = *(const uint4*)(kbase_h + koff + 8);                                   \
        kr2 = *(const uint4*)(kbase_l + koff);                                       \
        kr3 = *(const uint4*)(kbase_l + koff + 8);                                   \
        int voff = (KT)*32;                                                          \
        vr0 = *(const uint4*)(vbase_h + voff);                                       \
        vr1 = *(const uint4*)(vbase_h + voff + 8);                                   \
        vr2 = *(const uint4*)(vbase_l + voff);                                       \
        vr3 = *(const uint4*)(vbase_l + voff + 8);                                   \
    }

    LOADT(kts);
    for (int kt = kts; kt < kte; ++kt) {
        int k0 = kt * 32;
        __syncthreads();  // previous tile's LDS reads done
        *(uint4*)&Ksh[key_k][kc] = kr0;
        *(uint4*)&Ksh[key_k][kc + 8] = kr1;
        *(uint4*)&Ksl[key_k][kc] = kr2;
        *(uint4*)&Ksl[key_k][kc + 8] = kr3;
        *(uint4*)&Vsh[d_v][vc] = vr0;
        *(uint4*)&Vsh[d_v][vc + 8] = vr1;
        *(uint4*)&Vsl[d_v][vc] = vr2;
        *(uint4*)&Vsl[d_v][vc + 8] = vr3;
        __syncthreads();
        if (kt + 1 < kte) LOADT(kt + 1);  // prefetch next tile under compute
        if (kt < ntw) {
            f32x4 s[2];
            s[0] = (f32x4){0.f, 0.f, 0.f, 0.f};
            s[1] = (f32x4){0.f, 0.f, 0.f, 0.f};
#pragma unroll
            for (int nt = 0; nt < 2; ++nt)
#pragma unroll
                for (int c = 0; c < 4; ++c) {
                    bf16x8 kh = *(const bf16x8*)&Ksh[nt * 16 + lr][c * 32 + lq * 8];
                    bf16x8 kl = *(const bf16x8*)&Ksl[nt * 16 + lr][c * 32 + lq * 8];
                    s[nt] = MFMA16(qh[c], kh, s[nt]);
                    s[nt] = MFMA16(ql[c], kh, s[nt]);
                    s[nt] = MFMA16(qh[c], kl, s[nt]);
                }
            int gr_base = q0 + wave * 16 + lq * 4;
#pragma unroll
            for (int nt = 0; nt < 2; ++nt) {
                int gc = k0 + nt * 16 + lr;
#pragma unroll
                for (int p = 0; p < 4; ++p) {
                    float sv = s[nt][p] * scale;
                    if (gc > gr_base + p) sv = -1e30f;
                    s[nt][p] = sv;
                }
            }
            float alpha[4];
#pragma unroll
            for (int p = 0; p < 4; ++p) {
                float mx = fmaxf(s[0][p], s[1][p]);
#pragma unroll
                for (int off = 1; off < 16; off <<= 1) mx = fmaxf(mx, __shfl_xor(mx, off));
                float mn = fmaxf(m_r[p], mx);
                alpha[p] = __expf(m_r[p] - mn);
                float p0 = __expf(s[0][p] - mn);
                float p1 = __expf(s[1][p] - mn);
                float ps = p0 + p1;
#pragma unroll
                for (int off = 1; off < 16; off <<= 1) ps += __shfl_xor(ps, off);
                l_r[p] = l_r[p] * alpha[p] + ps;
                m_r[p] = mn;
                int r = lq * 4 + p;
                unsigned short h0 = f2bf(p0);
                Ph[wave][r][lr] = (short)h0;
                Pl[wave][r][lr] = (short)f2bf(p0 - bf2f(h0));
                unsigned short h1 = f2bf(p1);
                Ph[wave][r][lr + 16] = (short)h1;
                Pl[wave][r][lr + 16] = (short)f2bf(p1 - bf2f(h1));
            }
            bf16x8 pah = *(const bf16x8*)&Ph[wave][lr][lq * 8];
            bf16x8 pal = *(const bf16x8*)&Pl[wave][lr][lq * 8];
#pragma unroll
            for (int nt = 0; nt < 8; ++nt) {
#pragma unroll
                for (int p = 0; p < 4; ++p) o[nt][p] *= alpha[p];
                bf16x8 vh = *(const bf16x8*)&Vsh[nt * 16 + lr][lq * 8];
                bf16x8 vl = *(const bf16x8*)&Vsl[nt * 16 + lr][lq * 8];
                o[nt] = MFMA16(pah, vh, o[nt]);
                o[nt] = MFMA16(pal, vh, o[nt]);
                o[nt] = MFMA16(pah, vl, o[nt]);
            }
        }
    }
#undef LOADT
    // write un-normalized partials (o, m, l), compact causal slot index
    int pbase = h * NPSLOT + cqb_of(qb) + sp;
    float* porow = po + (size_t)pbase * (64 * 128);
#pragma unroll
    for (int nt = 0; nt < 8; ++nt)
#pragma unroll
        for (int p = 0; p < 4; ++p) {
            int row = wave * 16 + lq * 4 + p;
            porow[row * 128 + nt * 16 + lr] = o[nt][p];
        }
    if (lr == 0) {
#pragma unroll
        for (int p = 0; p < 4; ++p) {
            int row = wave * 16 + lq * 4 + p;
            pm[(size_t)pbase * 64 + row] = m_r[p];
            pl[(size_t)pbase * 64 + row] = l_r[p];
        }
    }
}

// merge split-K partials -> bf16 hi/lo attention output
__global__ __launch_bounds__(256) void attn_merge(const float* __restrict__ po,
                                                  const float* __restrict__ pm,
                                                  const float* __restrict__ pl,
                                                  unsigned short* __restrict__ Oh,
                                                  unsigned short* __restrict__ Ol) {
    int h = blockIdx.x, qb = blockIdx.y;
    int nact = qb / 4 + 1;  // ceil((qb+1)*64 / SPLITK)
    int tid = threadIdx.x;
    int row = tid >> 2;
    int c0 = (tid & 3) * 32;
    int pb = h * NPSLOT + cqb_of(qb);
    float ms[ASPLIT], ws[ASPLIT];
    float mstar = -1e30f;
#pragma unroll
    for (int s = 0; s < ASPLIT; ++s)
        if (s < nact) {
            ms[s] = pm[(size_t)(pb + s) * 64 + row];
            mstar = fmaxf(mstar, ms[s]);
        }
    float lstar = 0.f;
#pragma unroll
    for (int s = 0; s < ASPLIT; ++s)
        if (s < nact) {
            ws[s] = __expf(ms[s] - mstar);
            lstar += ws[s] * pl[(size_t)(pb + s) * 64 + row];
        }
    float linv = 1.f / lstar;
    size_t obase = (size_t)(qb * 64 + row) * H + h * HD + c0;
#pragma unroll
    for (int j = 0; j < 32; j += 4) {
        float acc[4] = {0.f, 0.f, 0.f, 0.f};
#pragma unroll
        for (int s = 0; s < ASPLIT; ++s)
            if (s < nact) {
                float4 v =
                    *(const float4*)&po[(size_t)(pb + s) * (64 * 128) + row * 128 + c0 + j];
                acc[0] += ws[s] * v.x;
                acc[1] += ws[s] * v.y;
                acc[2] += ws[s] * v.z;
                acc[3] += ws[s] * v.w;
            }
#pragma unroll
        for (int q = 0; q < 4; ++q) {
            float v = acc[q] * linv;
            unsigned short hb = f2bf(v);
            Oh[obase + j + q] = hb;
            Ol[obase + j + q] = f2bf(v - bf2f(hb));
        }
    }
}

// ---------------- router ----------------
__global__ void router_kernel(const float* __restrict__ logits, const float* __restrict__ bias,
                              int* __restrict__ topk_idx, float* __restrict__ topkw) {
    int t = blockIdx.x * 256 + threadIdx.x;
    if (t >= T) return;
    float sc[NE], sfc[NE];
    for (int e = 0; e < NE; ++e) {
        float s = 1.f / (1.f + expf(-logits[(size_t)t * NE + e]));
        sc[e] = s;
        sfc[e] = s + bias[e];
    }
    float gs[NG];
    for (int g = 0; g < NG; ++g) {
        float m1 = -1e30f, m2 = -1e30f;
        for (int i = 0; i < 4; ++i) {
            float v = sfc[g * 4 + i];
            if (v > m1) { m2 = m1; m1 = v; }
            else if (v > m2) m2 = v;
        }
        gs[g] = m1 + m2;
    }
    bool gmask[NG];
    for (int g = 0; g < NG; ++g) gmask[g] = false;
    for (int r = 0; r < 4; ++r) {
        int bi = 0; float bv = -1e30f;
        for (int g = 0; g < NG; ++g)
            if (gs[g] > bv) { bv = gs[g]; bi = g; }
        gmask[bi] = true;
        gs[bi] = -1e30f;
    }
    float msfc[NE];
    for (int e = 0; e < NE; ++e) msfc[e] = gmask[e >> 2] ? sfc[e] : 0.f;
    int idx[TOPK]; float w[TOPK]; float wsum = 0.f;
    for (int r = 0; r < TOPK; ++r) {
        int bi = 0; float bv = -1e30f;
        for (int e = 0; e < NE; ++e)
            if (msfc[e] > bv) { bv = msfc[e]; bi = e; }
        idx[r] = bi;
        msfc[bi] = -1e30f;
        w[r] = sc[bi];
        wsum += w[r];
    }
    float inv = RSF / (wsum + 1e-20f);
    for (int r = 0; r < TOPK; ++r) {
        topk_idx[(size_t)t * TOPK + r] = idx[r];
        topkw[(size_t)t * TOPK + r] = w[r] * inv;
    }
}

// fused zero + count + scan + fill (single block)
__global__ void bucket_kernel(const int* __restrict__ topk_idx, int* __restrict__ counts,
                              int* __restrict__ offs, int* __restrict__ tok_of,
                              int* __restrict__ slot_of) {
    __shared__ int cnt[NE], off[NE], fil[NE];
    int tid = threadIdx.x;
    if (tid < NE) { cnt[tid] = 0; fil[tid] = 0; }
    __syncthreads();
    for (int i = tid; i < T * TOPK; i += 256) atomicAdd(&cnt[topk_idx[i]], 1);
    __syncthreads();
    if (tid == 0) {
        int a = 0;
        for (int e = 0; e < NE; ++e) { off[e] = a; a += cnt[e]; }
    }
    __syncthreads();
    if (tid < NE) { counts[tid] = cnt[tid]; offs[tid] = off[tid]; }
    for (int i = tid; i < T * TOPK; i += 256) {
        int e = topk_idx[i];
        int p = off[e] + atomicAdd(&fil[e], 1);
        tok_of[p] = i >> 2;
        slot_of[i] = p;
    }
}

// ---------------- dual up-proj: 64m x 64n tile, reg-staged depth-1, padded LDS -------
// 4 waves each own a 32x32 output sub-tile. Staging: thread -> (row tid>>2, 16-short
// piece tid&3), loading TWO uint4 (16 shorts) per array per K-step. Coverage:
// 64 rows x 4 pieces x 16 shorts = 4096 shorts per array.
__global__ __launch_bounds__(256) void up_mfma2(
    const unsigned short* __restrict__ Xb, const unsigned short* __restrict__ Gt,
    const unsigned short* __restrict__ Ut, size_t wstride, const int* __restrict__ tok_of,
    const int* __restrict__ offs, const int* __restrict__ counts, int eoff,
    unsigned short* __restrict__ outb, int ldo) {
    int zl = blockIdx.z;
    int e = eoff + zl;
    int cnt = counts ? counts[e] : T;
    int base = offs ? offs[e] : 0;
    int m0 = blockIdx.y * 64;
    if (m0 >= cnt) return;
    int n0 = blockIdx.x * 64;
    const unsigned short* gt = Gt + (size_t)zl * wstride;
    const unsigned short* ut = Ut + (size_t)zl * wstride;
    __shared__ __attribute__((aligned(16))) short As[2][64][KP];
    __shared__ __attribute__((aligned(16))) short Gs[2][64][KP];
    __shared__ __attribute__((aligned(16))) short Us[2][64][KP];
    __shared__ int toks[64];
    int tid = threadIdx.x;
    if (tid < 64) {
        int m = m0 + tid;
        if (m >= cnt) m = cnt - 1;
        toks[tid] = tok_of ? tok_of[base + m] : m;
    }
    __syncthreads();
    int wave = tid >> 6, lane = tid & 63;
    int lr = lane & 15, lq = lane >> 4;
    int wm = (wave >> 1) * 32, wn = (wave & 1) * 32;
    // staging: row = tid>>2, piece sq = tid&3 (16 shorts = 2 uint4), chunk = sq>>1
    int srow = tid >> 2, sq = tid & 3;
    int sc = sq >> 1, soff = (sq & 1) * 16;
    int skoff = sq * 16;
    const unsigned short* aptr = Xb + (size_t)toks[srow] * H + skoff;
    const unsigned short* gptr = gt + (size_t)(n0 + srow) * H + skoff;
    const unsigned short* uptr = ut + (size_t)(n0 + srow) * H + skoff;
    f32x4 ag[2][2], au[2][2];
#pragma unroll
    for (int i = 0; i < 2; ++i)
#pragma unroll
        for (int j = 0; j < 2; ++j) {
            ag[i][j] = (f32x4){0.f, 0.f, 0.f, 0.f};
            au[i][j] = (f32x4){0.f, 0.f, 0.f, 0.f};
        }
    uint4 ra0, ra1, rg0, rg1, ru0, ru1;
#define LOADU(K0)                                      \
    {                                                  \
        ra0 = *(const uint4*)(aptr + (K0));            \
        ra1 = *(const uint4*)(aptr + (K0) + 8);        \
        rg0 = *(const uint4*)(gptr + (K0));            \
        rg1 = *(const uint4*)(gptr + (K0) + 8);        \
        ru0 = *(const uint4*)(uptr + (K0));            \
        ru1 = *(const uint4*)(uptr + (K0) + 8);        \
    }
    LOADU(0);
    for (int k0 = 0; k0 < H; k0 += 64) {
        __syncthreads();  // previous iteration's LDS reads done
        *(uint4*)&As[sc][srow][soff] = ra0;
        *(uint4*)&As[sc][srow][soff + 8] = ra1;
        *(uint4*)&Gs[sc][srow][soff] = rg0;
        *(uint4*)&Gs[sc][srow][soff + 8] = rg1;
        *(uint4*)&Us[sc][srow][soff] = ru0;
        *(uint4*)&Us[sc][srow][soff + 8] = ru1;
        __syncthreads();
        if (k0 + 64 < H) LOADU(k0 + 64);  // prefetch next tile under compute
#pragma unroll
        for (int c = 0; c < 2; ++c) {
            bf16x8 a[2], gg[2], uu[2];
#pragma unroll
            for (int mt = 0; mt < 2; ++mt)
                a[mt] = *(const bf16x8*)&As[c][wm + mt * 16 + lr][lq * 8];
#pragma unroll
            for (int nt = 0; nt < 2; ++nt) {
                gg[nt] = *(const bf16x8*)&Gs[c][wn + nt * 16 + lr][lq * 8];
                uu[nt] = *(const bf16x8*)&Us[c][wn + nt * 16 + lr][lq * 8];
            }
#pragma unroll
            for (int mt = 0; mt < 2; ++mt)
#pragma unroll
                for (int nt = 0; nt < 2; ++nt) {
                    ag[mt][nt] = MFMA16(a[mt], gg[nt], ag[mt][nt]);
                    au[mt][nt] = MFMA16(a[mt], uu[nt], au[mt][nt]);
                }
        }
    }
#undef LOADU
#pragma unroll
    for (int mt = 0; mt < 2; ++mt)
#pragma unroll
        for (int nt = 0; nt < 2; ++nt)
#pragma unroll
            for (int p = 0; p < 4; ++p) {
                int m = m0 + wm + mt * 16 + lq * 4 + p;
                if (m >= cnt) continue;
                int orow = tok_of ? base + m : m;
                int col = n0 + wn + nt * 16 + lr;
                float gv = ag[mt][nt][p], uv = au[mt][nt][p];
                float sv = gv / (1.f + __expf(-gv)) * uv;
                outb[(size_t)orow * ldo + col] = f2bf(sv);
            }
}

// ---------------- down-proj: reg-staged depth-1 prefetch + padded LDS, fp32 out ------
__global__ __launch_bounds__(256) void down_mfma2(const unsigned short* __restrict__ Ab, int K,
                                                  const unsigned short* __restrict__ Wt,
                                                  size_t wstride, const int* __restrict__ offs,
                                                  const int* __restrict__ counts, int eoff,
                                                  float* __restrict__ Co) {
    int zl = blockIdx.z;
    int e = eoff + zl;
    int cnt = counts ? counts[e] : T;
    int base = offs ? offs[e] : 0;
    int m0 = blockIdx.y * 128;
    if (m0 >= cnt) return;
    int n0 = blockIdx.x * 128;
    const unsigned short* wt = Wt + (size_t)zl * wstride;
    __shared__ __attribute__((aligned(16))) short As[2][128][KP];
    __shared__ __attribute__((aligned(16))) short Bs[2][128][KP];
    int tid = threadIdx.x;
    int wave = tid >> 6, lane = tid & 63;
    int lr = lane & 15, lq = lane >> 4;
    int wm = (wave >> 1) * 64, wn = (wave & 1) * 64;
    int srow = lane >> 2, skb = (lane & 3) * 8;
    const unsigned short* aptr[2];
    const unsigned short* bptr[2];
#pragma unroll
    for (int p = 0; p < 2; ++p) {
        int m = m0 + wave * 32 + p * 16 + srow;
        if (m >= cnt) m = cnt - 1;
        aptr[p] = Ab + (size_t)(base + m) * K + skb;
        bptr[p] = wt + (size_t)(n0 + wave * 32 + p * 16 + srow) * K + skb;
    }
    f32x4 acc[4][4];
#pragma unroll
    for (int i = 0; i < 4; ++i)
#pragma unroll
        for (int j = 0; j < 4; ++j) acc[i][j] = (f32x4){0.f, 0.f, 0.f, 0.f};
    uint4 ra00, ra01, ra10, ra11, rb00, rb01, rb10, rb11;
#define LOADD(K0)                                          \
    {                                                      \
        ra00 = *(const uint4*)(aptr[0] + (K0));            \
        ra01 = *(const uint4*)(aptr[1] + (K0));            \
        ra10 = *(const uint4*)(aptr[0] + (K0) + 32);       \
        ra11 = *(const uint4*)(aptr[1] + (K0) + 32);       \
        rb00 = *(const uint4*)(bptr[0] + (K0));            \
        rb01 = *(const uint4*)(bptr[1] + (K0));            \
        rb10 = *(const uint4*)(bptr[0] + (K0) + 32);       \
        rb11 = *(const uint4*)(bptr[1] + (K0) + 32);       \
    }
    LOADD(0);
    for (int k0 = 0; k0 < K; k0 += 64) {
        __syncthreads();  // previous iteration's LDS reads done
        *(uint4*)&As[0][wave * 32 + srow][skb] = ra00;
        *(uint4*)&As[0][wave * 32 + 16 + srow][skb] = ra01;
        *(uint4*)&As[1][wave * 32 + srow][skb] = ra10;
        *(uint4*)&As[1][wave * 32 + 16 + srow][skb] = ra11;
        *(uint4*)&Bs[0][wave * 32 + srow][skb] = rb00;
        *(uint4*)&Bs[0][wave * 32 + 16 + srow][skb] = rb01;
        *(uint4*)&Bs[1][wave * 32 + srow][skb] = rb10;
        *(uint4*)&Bs[1][wave * 32 + 16 + srow][skb] = rb11;
        __syncthreads();
        if (k0 + 64 < K) LOADD(k0 + 64);  // prefetch next tile under compute
#pragma unroll
        for (int c = 0; c < 2; ++c) {
            bf16x8 a[4], b[4];
#pragma unroll
            for (int mt = 0; mt < 4; ++mt)
                a[mt] = *(const bf16x8*)&As[c][wm + mt * 16 + lr][lq * 8];
#pragma unroll
            for (int nt = 0; nt < 4; ++nt)
                b[nt] = *(const bf16x8*)&Bs[c][wn + nt * 16 + lr][lq * 8];
#pragma unroll
            for (int mt = 0; mt < 4; ++mt)
#pragma unroll
                for (int nt = 0; nt < 4; ++nt) acc[mt][nt] = MFMA16(a[mt], b[nt], acc[mt][nt]);
        }
    }
#undef LOADD
#pragma unroll
    for (int mt = 0; mt < 4; ++mt)
#pragma unroll
        for (int nt = 0; nt < 4; ++nt)
#pragma unroll
            for (int p = 0; p < 4; ++p) {
                int m = m0 + wm + mt * 16 + lq * 4 + p;
                if (m >= cnt) continue;
                int col = n0 + wn + nt * 16 + lr;
                Co[(size_t)(base + m) * H + col] = acc[mt][nt][p];
            }
}

// ---------------- final combine ----------------
__global__ void combine_kernel(const float* __restrict__ o_slot, const int* __restrict__ slot_of,
                               const float* __restrict__ topkw, const float* __restrict__ h2,
                               const float* __restrict__ sharedo, float* __restrict__ out) {
    int t = blockIdx.x;
    int d = threadIdx.x * 4;
    float4 a = *(const float4*)&h2[(size_t)t * H + d];
    float4 b = *(const float4*)&sharedo[(size_t)t * H + d];
    float4 acc = make_float4(a.x + b.x, a.y + b.y, a.z + b.z, a.w + b.w);
#pragma unroll
    for (int r = 0; r < TOPK; ++r) {
        int s = slot_of[t * TOPK + r];
        float w = topkw[t * TOPK + r];
        float4 v = *(const float4*)&o_slot[(size_t)s * H + d];
        acc.x += w * v.x; acc.y += w * v.y; acc.z += w * v.z; acc.w += w * v.w;
    }
    *(float4*)&out[(size_t)t * H + d] = acc;
}

// ---------------- launch ----------------
extern "C" void kernel_launch(void* const* d_in, const int* in_sizes, int n_in,
                              void* d_out, int out_size, void* d_ws, size_t ws_size,
                              hipStream_t stream) {
    const float* hidden = (const float*)d_in[0];
    const int* pos = (const int*)d_in[1];
    const float* ln1w = (const float*)d_in[2];
    const float* ln2w = (const float*)d_in[3];
    const float* q_w = (const float*)d_in[4];
    const float* k_w = (const float*)d_in[5];
    const float* v_w = (const float*)d_in[6];
    const float* o_w = (const float*)d_in[7];
    const float* router_w = (const float*)d_in[8];
    const float* router_b = (const float*)d_in[9];
    const float* eg_w = (const float*)d_in[10];
    const float* eu_w = (const float*)d_in[11];
    const float* ed_w = (const float*)d_in[12];
    const float* sg_w = (const float*)d_in[13];
    const float* su_w = (const float*)d_in[14];
    const float* sd_w = (const float*)d_in[15];
    float* out = (float*)d_out;

    float* f = (float*)d_ws;
    // --- arena region (32 MB): attention-phase buffers, reused for shared-expert weights
    float* xslot = f;   f += (size_t)T * H;          // 4 MB: Xh/Xl; then bf16 K/V for attn
    float* qb = f;      f += (size_t)T * H;          // 4 MB
    float* kb = f;      f += (size_t)T * NKV * HD;   // 2 MB
    float* vb = f;      f += (size_t)T * NKV * HD;   // 2 MB
    float* aoslot = f;  f += (size_t)T * H;          // 4 MB: attn out bf16 hi/lo
    float* ext = f;     f += (size_t)4 * 1024 * 1024;  // 16 MB: split qkv/o weights
    // --- persistent buffers
    float* h2 = f;      f += (size_t)T * H;
    float* h_ln2f = f;  f += (size_t)T * H;
    float* logits = f;  f += (size_t)T * NE;
    float* topkw = f;   f += (size_t)T * TOPK;
    float* o_slot = f;  f += (size_t)T * TOPK * H;   // 16 MB; doubles as attn split po
    float* sharedo = f; f += (size_t)T * H;          // 4 MB
    unsigned short* h_ln2b = (unsigned short*)f;
    unsigned short* abuf = h_ln2b + (size_t)T * H;
    unsigned short* ashared = abuf + (size_t)T * TOPK * MI;
    int* topk_idx = (int*)(ashared + (size_t)T * SI);
    int* counts = topk_idx + T * TOPK;
    int* fills = counts + NE;   // unused (kept for layout stability)
    int* offs = fills + NE;
    int* tok_of = offs + NE;
    int* slot_of = tok_of + T * TOPK;
    (void)fills;

    // big all-expert transposed-weight region at fixed 80 MB offset (ws = 256 MiB per
    // harness poison evidence); 96 MB total. Guarded by ws_size with grouped fallback.
    unsigned short* wT = (unsigned short*)((char*)d_ws + (size_t)80 * 1024 * 1024);
    unsigned short* egTall = wT;                              // 32 MB
    unsigned short* euTall = egTall + (size_t)NE * H * MI;    // 32 MB
    unsigned short* edTall = euTall + (size_t)NE * H * MI;    // 32 MB
    bool big_ws = ws_size >= (size_t)(80 + 96 + 1) * 1024 * 1024;

    // split-weight views in the 16 MB extension (dead until MoE overwrites arena)
    unsigned short* We = (unsigned short*)ext;
    const size_t HH = (size_t)H * H;          // 1M elements
    const size_t KH = (size_t)NKV * HD * H;   // 512K elements
    unsigned short* Wqh = We;
    unsigned short* Wql = Wqh + HH;
    unsigned short* Wkh = Wql + HH;
    unsigned short* Wkl = Wkh + KH;
    unsigned short* Wvh = Wkl + KH;
    unsigned short* Wvl = Wvh + KH;
    unsigned short* Woh = Wvl + KH;
    unsigned short* Wol = Woh + HH;

    unsigned short* Xh = (unsigned short*)xslot;
    unsigned short* Xl = Xh + (size_t)T * H;
    unsigned short* Aoh = (unsigned short*)aoslot;
    unsigned short* Aol = Aoh + (size_t)T * H;

    // bf16 K/V for attention (overlay xslot AFTER gemm3_qkv consumed Xh/Xl)
    unsigned short* Khg = (unsigned short*)xslot;          // [T][NKV*HD]
    unsigned short* Klg = Khg + (size_t)T * NKV * HD;
    unsigned short* VTh = Klg + (size_t)T * NKV * HD;      // [NKV*HD][T]
    unsigned short* VTl = VTh + (size_t)T * NKV * HD;

    // attn split-K partial views (live only between attn_split and attn_merge)
    float* attn_po = o_slot;                 // 320 slots * 64*128 fp32 = 10.5 MB
    float* attn_pm = (float*)abuf;           // 320*64 fp32
    float* attn_pl = attn_pm + (size_t)NH * NPSLOT * 64;

    // arena views (grouped fallback + shared expert)
    unsigned short* arena = (unsigned short*)xslot;
    unsigned short* egT = arena;
    unsigned short* euT = arena + (size_t)16 * H * MI;
    unsigned short* edT = arena;
    unsigned short* sgT = arena;
    unsigned short* suT = arena + (size_t)H * SI;
    unsigned short* sdT = arena;

    dim3 b256(256);

    // one-shot hi/lo splits (weights + ln1 activations)
    split_w4<<<dim3(HH / (256 * 4), 1, 4), b256, 0, stream>>>(q_w, k_w, v_w, o_w, Wqh, Wql,
                                                              Wkh, Wkl, Wvh, Wvl, Woh, Wol);
    rmsnorm_split_kernel<<<T, b256, 0, stream>>>(hidden, ln1w, Xh, Xl);

    gemm3_qkv<<<dim3(32, 8), b256, 0, stream>>>(Xh, Xl, Wqh, Wql, Wkh, Wkl, Wvh, Wvl,
                                                qb, kb, vb);
    {
        int tot = T * NH * 64 + T * NKV * 64;
        rope_kernel<<<(tot + 255) / 256, b256, 0, stream>>>(qb, kb, pos, Khg, Klg);
    }
    vt_split<<<dim3(T / 64, (NKV * HD) / 64), b256, 0, stream>>>(vb, VTh, VTl);
    attn_split<<<dim3(NH, T / 64, ASPLIT), b256, 0, stream>>>(qb, Khg, Klg, VTh, VTl,
                                                              attn_po, attn_pm, attn_pl);
    attn_merge<<<dim3(NH, T / 64), b256, 0, stream>>>(attn_po, attn_pm, attn_pl, Aoh, Aol);
    gemm3_res<<<dim3(16, 8), b256, 0, stream>>>(Aoh, Aol, Woh, Wol, hidden, h2);
    rmsnorm_dual_kernel<<<T, b256, 0, stream>>>(h2, ln2w, h_ln2f, h_ln2b);

    router_logits_kernel<<<T, b256, 0, stream>>>(h_ln2f, router_w, logits);
    router_kernel<<<(T + 255) / 256, b256, 0, stream>>>(logits, router_b, topk_idx, topkw);
    bucket_kernel<<<1, b256, 0, stream>>>(topk_idx, counts, offs, tok_of, slot_of);

    if (big_ws) {
        // ---- MoE, single pass over all 32 experts (full-chip up/down dispatches) ----
        transpose_cvt<<<dim3(MI / 64, H / 64, NE), b256, 0, stream>>>(eg_w, egTall, H, MI, 0);
        transpose_cvt<<<dim3(MI / 64, H / 64, NE), b256, 0, stream>>>(eu_w, euTall, H, MI, 0);
        up_mfma2<<<dim3(MI / 64, T / 64, NE), b256, 0, stream>>>(
            h_ln2b, egTall, euTall, (size_t)H * MI, tok_of, offs, counts, 0, abuf, MI);
        transpose_cvt<<<dim3(H / 64, MI / 64, NE), b256, 0, stream>>>(ed_w, edTall, MI, H, 0);
        down_mfma2<<<dim3(H / 128, 8, NE), b256, 0, stream>>>(
            abuf, MI, edTall, (size_t)MI * H, offs, counts, 0, o_slot);
    } else {
        // ---- fallback: 2 expert groups of 16 through the 32 MB arena ----
        for (int g = 0; g < 2; ++g) {
            int eo = g * 16;
            transpose_cvt<<<dim3(MI / 64, H / 64, 16), b256, 0, stream>>>(eg_w, egT, H, MI, eo);
            transpose_cvt<<<dim3(MI / 64, H / 64, 16), b256, 0, stream>>>(eu_w, euT, H, MI, eo);
            up_mfma2<<<dim3(MI / 64, T / 64, 16), b256, 0, stream>>>(
                h_ln2b, egT, euT, (size_t)H * MI, tok_of, offs, counts, eo, abuf, MI);
        }
        for (int g = 0; g < 2; ++g) {
            int eo = g * 16;
            transpose_cvt<<<dim3(H / 64, MI / 64, 16), b256, 0, stream>>>(ed_w, edT, MI, H, eo);
            down_mfma2<<<dim3(H / 128, 8, 16), b256, 0, stream>>>(
                abuf, MI, edT, (size_t)MI * H, offs, counts, eo, o_slot);
        }
    }
    // ---- shared expert (arena; xslot is free after attention) ----
    transpose_cvt<<<dim3(SI / 64, H / 64, 1), b256, 0, stream>>>(sg_w, sgT, H, SI, 0);
    transpose_cvt<<<dim3(SI / 64, H / 64, 1), b256, 0, stream>>>(su_w, suT, H, SI, 0);
    up_mfma2<<<dim3(SI / 64, T / 64, 1), b256, 0, stream>>>(
        h_ln2b, sgT, suT, 0, nullptr, nullptr, nullptr, 0, ashared, SI);
    transpose_cvt<<<dim3(H / 64, SI / 64, 1), b256, 0, stream>>>(sd_w, sdT, SI, H, 0);
    down_mfma2<<<dim3(H / 128, T / 128, 1), b256, 0, stream>>>(
        ashared, SI, sdT, 0, nullptr, nullptr, 0, sharedo);

    combine_kernel<<<T, b256, 0, stream>>>(o_slot, slot_of, topkw, h2, sharedo, out);
}